// Round 1
// 2981.281 us; speedup vs baseline: 1.0481x; 1.0481x over previous
//
#include <hip/hip_runtime.h>

// Problem constants
constexpr int B   = 16;
constexpr int N   = 768;
constexpr int FIN = 56;
constexpr int D   = 140;
constexpr int L   = 4;
constexpr int DF  = 128;
constexpr int NN  = N * N;        // 589824
constexpr int BND = B * N * D;    // 1720320
constexpr int BNN = B * NN;       // 9437184

// pooling split
constexpr int PROWS  = 16;            // rows per pooling block
constexpr int NCHUNK = N / PROWS;     // 48 partials per batch

// ---------------------------------------------------------------------------
// K1: x = c_hs @ W_emb   [B*N,56] @ [56,140]
__global__ __launch_bounds__(256) void k_embed(const float* __restrict__ chs,
                                               const float* __restrict__ Wemb,
                                               float* __restrict__ x) {
    int idx = blockIdx.x * 256 + threadIdx.x;
    if (idx >= BND) return;
    int d  = idx % D;
    int bn = idx / D;
    const float* row = chs + bn * FIN;
    float acc = 0.f;
#pragma unroll 8
    for (int f = 0; f < FIN; ++f) acc += row[f] * Wemb[f * D + d];
    x[idx] = acc;
}

// ---------------------------------------------------------------------------
// K2: adj2 = formulate(c_adjs2)  (elementwise, mask from valid/num_atoms)
__global__ __launch_bounds__(256) void k_adj2(const float* __restrict__ a2,
                                              const int* __restrict__ valid,
                                              const int* __restrict__ natoms,
                                              const float* __restrict__ mu,
                                              const float* __restrict__ dev,
                                              float* __restrict__ out) {
    int idx = blockIdx.x * 256 + threadIdx.x;
    if (idx >= BNN) return;
    int b   = idx / NN;
    int rem = idx - b * NN;
    int i   = rem / N;
    int j   = rem - i * N;
    float a = a2[idx];
    int vi = valid[b * N + i];
    int vj = valid[b * N + j];
    int n  = natoms[b];
    bool mask = (vi && !vj && (j < n)) || (vj && !vi && (i < n));
    float dmu = a - mu[0];
    float g = (a <= 10.f) ? expf(-dmu * dmu / dev[0]) : 0.f;
    out[idx] = mask ? g : a;
}

// ---------------------------------------------------------------------------
// K3: out[bn,d] = in[bn,:] @ W[:,d] (+ bias)   — [B*N,140]@[140,140]
__global__ __launch_bounds__(256) void k_linear140(const float* __restrict__ in,
                                                   const float* __restrict__ W,
                                                   const float* __restrict__ bias,
                                                   float* __restrict__ out) {
    int idx = blockIdx.x * 256 + threadIdx.x;
    if (idx >= BND) return;
    int d  = idx % D;
    int bn = idx / D;
    const float* row = in + bn * D;
    float acc = bias ? bias[d] : 0.f;
#pragma unroll 4
    for (int k = 0; k < D; ++k) acc += row[k] * W[k * D + d];
    out[idx] = acc;
}

// ---------------------------------------------------------------------------
// K4: E[b,j,k] = hA[b,j,:]·h[b,k,:] + hA[b,k,:]·h[b,j,:]  (symmetric).
// Upper-triangle 32x32 tiles only; mirror write. Two LDS phases to stay <64KB.
__global__ __launch_bounds__(256) void k_e(const float* __restrict__ h,
                                           const float* __restrict__ hA,
                                           float* __restrict__ E) {
    int tj = blockIdx.x, tk = blockIdx.y, b = blockIdx.z;
    if (tj > tk) return;
    __shared__ float s0[32][141];  // rows of j-tile
    __shared__ float s1[32][141];  // rows of k-tile
    int tid   = threadIdx.x;
    int col   = tid & 31;
    int rbase = tid >> 5;
    int j0 = tj * 32, k0 = tk * 32;
    const float* hb = h  + (size_t)b * N * D;
    const float* ab = hA + (size_t)b * N * D;

    float acc[4] = {0.f, 0.f, 0.f, 0.f};

    // phase 1: acc += hA[j]·h[k]
    for (int idx = tid; idx < 32 * D; idx += 256) {
        int r = idx / D, c = idx - r * D;
        s0[r][c] = ab[(size_t)(j0 + r) * D + c];
        s1[r][c] = hb[(size_t)(k0 + r) * D + c];
    }
    __syncthreads();
#pragma unroll 4
    for (int kk = 0; kk < D; ++kk) {
        float v = s1[col][kk];
#pragma unroll
        for (int q = 0; q < 4; ++q) acc[q] += s0[rbase + q * 8][kk] * v;
    }
    __syncthreads();

    // phase 2: acc += h[j]·hA[k]
    for (int idx = tid; idx < 32 * D; idx += 256) {
        int r = idx / D, c = idx - r * D;
        s0[r][c] = hb[(size_t)(j0 + r) * D + c];
        s1[r][c] = ab[(size_t)(k0 + r) * D + c];
    }
    __syncthreads();
#pragma unroll 4
    for (int kk = 0; kk < D; ++kk) {
        float v = s1[col][kk];
#pragma unroll
        for (int q = 0; q < 4; ++q) acc[q] += s0[rbase + q * 8][kk] * v;
    }

    float* Eb = E + (size_t)b * NN;
#pragma unroll
    for (int q = 0; q < 4; ++q) {
        int j = j0 + rbase + q * 8;
        int k = k0 + col;
        float v = acc[q];
        Eb[(size_t)j * N + k] = v;
        Eb[(size_t)k * N + j] = v;   // mirror (same value on diagonal tile)
    }
}

// ---------------------------------------------------------------------------
// K5: column softmax over axis j of masked E, times adj.
// ATT[b,j,k] = softmax_j( adj>0 ? E : -9e15 ) * adj
// Block: 64 columns, 4 j-slices of threads. Two passes (online m,s; then write).
__global__ __launch_bounds__(256) void k_softmax(const float* __restrict__ E,
                                                 const float* __restrict__ adj,
                                                 float* __restrict__ ATT) {
    int b    = blockIdx.y;
    int lane = threadIdx.x & 63;
    int js   = threadIdx.x >> 6;   // 0..3
    int k    = blockIdx.x * 64 + lane;
    const float* Eb = E   + (size_t)b * NN;
    const float* Ab = adj + (size_t)b * NN;
    float*       Tb = ATT + (size_t)b * NN;

    float m = -3.0e38f, s = 0.f;
#pragma unroll 4
    for (int j = js; j < N; j += 4) {
        float av = Ab[(size_t)j * N + k];
        float ev = Eb[(size_t)j * N + k];
        float x  = (av > 0.f) ? ev : -9e15f;
        float nm = fmaxf(m, x);
        s = s * __expf(m - nm) + __expf(x - nm);
        m = nm;
    }
    __shared__ float sm[4][64], ss[4][64];
    sm[js][lane] = m;
    ss[js][lane] = s;
    __syncthreads();
    if (js == 0) {
        float M = sm[0][lane], S = ss[0][lane];
#pragma unroll
        for (int q = 1; q < 4; ++q) {
            float m2 = sm[q][lane], s2 = ss[q][lane];
            float nm = fmaxf(M, m2);
            S = S * __expf(M - nm) + s2 * __expf(m2 - nm);
            M = nm;
        }
        sm[0][lane] = M;
        ss[0][lane] = 1.f / S;
    }
    __syncthreads();
    float M = sm[0][lane], invS = ss[0][lane];
#pragma unroll 4
    for (int j = js; j < N; j += 4) {
        float av = Ab[(size_t)j * N + k];
        float ev = Eb[(size_t)j * N + k];
        float x  = (av > 0.f) ? ev : -9e15f;
        Tb[(size_t)j * N + k] = __expf(x - M) * invS * av;
    }
}

// ---------------------------------------------------------------------------
// K6: hp = relu(ATT @ h)   [768,768]@[768,140], 32x32-d tiles
__global__ __launch_bounds__(256) void k_ath(const float* __restrict__ ATT,
                                             const float* __restrict__ h,
                                             float* __restrict__ hp) {
    int ti = blockIdx.x, td = blockIdx.y, b = blockIdx.z;
    __shared__ float sA[32][33];
    __shared__ float sH[32][33];
    int tid   = threadIdx.x;
    int col   = tid & 31;
    int rbase = tid >> 5;
    int i0 = ti * 32, d0 = td * 32;
    const float* Tb = ATT + (size_t)b * NN;
    const float* hb = h + (size_t)b * N * D;
    float acc[4] = {0.f, 0.f, 0.f, 0.f};
    int d = d0 + col;
    for (int jt = 0; jt < N / 32; ++jt) {
        int j0 = jt * 32;
#pragma unroll
        for (int q = 0; q < 4; ++q) {
            int r = rbase + q * 8;
            sA[r][col] = Tb[(size_t)(i0 + r) * N + (j0 + col)];
            sH[r][col] = (d < D) ? hb[(size_t)(j0 + r) * D + d] : 0.f;
        }
        __syncthreads();
#pragma unroll 8
        for (int jj = 0; jj < 32; ++jj) {
            float hv = sH[jj][col];
#pragma unroll
            for (int q = 0; q < 4; ++q) acc[q] += sA[rbase + q * 8][jj] * hv;
        }
        __syncthreads();
    }
    if (d < D) {
#pragma unroll
        for (int q = 0; q < 4; ++q) {
            int i = i0 + rbase + q * 8;
            hp[(size_t)b * N * D + (size_t)i * D + d] = fmaxf(acc[q], 0.f);
        }
    }
}

// ---------------------------------------------------------------------------
// K7: gate combine. mode 0: g1 = coeff*x+(1-coeff)*hp
//                   mode 1: x  = (coeff*x+(1-coeff)*hp) - g1   (in place)
__global__ __launch_bounds__(64) void k_gate(const float* __restrict__ x,
                                             const float* __restrict__ hp,
                                             const float* __restrict__ gw,
                                             const float* __restrict__ gb,
                                             float* __restrict__ g1,
                                             float* __restrict__ xout,
                                             int mode) {
    int row  = blockIdx.x;           // 0..B*N-1
    int lane = threadIdx.x;
    const float* xr = x  + (size_t)row * D;
    const float* hr = hp + (size_t)row * D;
    float part = 0.f;
    for (int d = lane; d < D; d += 64) part += xr[d] * gw[d] + hr[d] * gw[D + d];
#pragma unroll
    for (int off = 32; off; off >>= 1) part += __shfl_xor(part, off);
    float c = 1.f / (1.f + __expf(-(part + gb[0])));
    for (int d = lane; d < D; d += 64) {
        float v = c * xr[d] + (1.f - c) * hr[d];
        if (mode == 0) g1[(size_t)row * D + d] = v;
        else           xout[(size_t)row * D + d] = v - g1[(size_t)row * D + d];
    }
}

// ---------------------------------------------------------------------------
// K8a: parallel ragged sum-pool, stage 1.
// grid (NCHUNK, B); block sums PROWS rows (clipped to num_atoms) into
// part[b][chunk][d]. 768 blocks -> fills the GPU; coalesced d-reads.
__global__ __launch_bounds__(256) void k_pool(const float* __restrict__ x,
                                              const int* __restrict__ natoms,
                                              float* __restrict__ part) {
    int c = blockIdx.x;              // chunk
    int b = blockIdx.y;              // batch
    int tid = threadIdx.x;
    if (tid >= D) return;
    int n  = natoms[b];
    int r0 = c * PROWS;
    int r1 = min(r0 + PROWS, n);
    const float* xb = x + (size_t)b * N * D;
    float acc = 0.f;
    for (int r = r0; r < r1; ++r) acc += xb[(size_t)r * D + tid];
    part[((size_t)b * NCHUNK + c) * D + tid] = acc;
}

// ---------------------------------------------------------------------------
// K8b: combine partials + 4-layer MLP + sigmoid. One block per batch.
__global__ __launch_bounds__(256) void k_final(const float* __restrict__ part,
                                               const float* __restrict__ w0, const float* __restrict__ b0,
                                               const float* __restrict__ w1, const float* __restrict__ b1,
                                               const float* __restrict__ w2, const float* __restrict__ b2,
                                               const float* __restrict__ w3, const float* __restrict__ b3,
                                               float* __restrict__ out) {
    int b   = blockIdx.x;
    int tid = threadIdx.x;
    __shared__ float pred[D];
    __shared__ float h0[DF], h1[DF], h2[DF];
    if (tid < D) {
        float acc = 0.f;
        const float* pb = part + (size_t)b * NCHUNK * D;
#pragma unroll 8
        for (int c = 0; c < NCHUNK; ++c) acc += pb[(size_t)c * D + tid];
        pred[tid] = acc;
    }
    __syncthreads();
    if (tid < DF) {
        float acc = b0[tid];
#pragma unroll 4
        for (int i = 0; i < D; ++i) acc += pred[i] * w0[i * DF + tid];
        h0[tid] = fmaxf(acc, 0.f);
    }
    __syncthreads();
    if (tid < DF) {
        float acc = b1[tid];
#pragma unroll 4
        for (int i = 0; i < DF; ++i) acc += h0[i] * w1[i * DF + tid];
        h1[tid] = fmaxf(acc, 0.f);
    }
    __syncthreads();
    if (tid < DF) {
        float acc = b2[tid];
#pragma unroll 4
        for (int i = 0; i < DF; ++i) acc += h1[i] * w2[i * DF + tid];
        h2[tid] = fmaxf(acc, 0.f);
    }
    __syncthreads();
    if (tid == 0) {
        float acc = b3[0];
        for (int i = 0; i < DF; ++i) acc += h2[i] * w3[i];
        out[b] = 1.f / (1.f + expf(-acc));
    }
}

// ---------------------------------------------------------------------------
extern "C" void kernel_launch(void* const* d_in, const int* in_sizes, int n_in,
                              void* d_out, int out_size, void* d_ws, size_t ws_size,
                              hipStream_t stream) {
    const float* c_hs  = (const float*)d_in[0];
    const float* adj1  = (const float*)d_in[1];
    const float* c_a2  = (const float*)d_in[2];
    const int*   valid = (const int*)d_in[3];
    const int*   nat   = (const int*)d_in[4];
    const float* Wemb  = (const float*)d_in[5];
    const float* gatW  = (const float*)d_in[6];
    const float* gatWb = (const float*)d_in[7];
    const float* gatA  = (const float*)d_in[8];
    const float* gatgw = (const float*)d_in[9];
    const float* gatgb = (const float*)d_in[10];
    const float* w0 = (const float*)d_in[11];
    const float* b0 = (const float*)d_in[12];
    const float* w1 = (const float*)d_in[13];
    const float* b1 = (const float*)d_in[14];
    const float* w2 = (const float*)d_in[15];
    const float* b2 = (const float*)d_in[16];
    const float* w3 = (const float*)d_in[17];
    const float* b3 = (const float*)d_in[18];
    const float* mu  = (const float*)d_in[19];
    const float* dev = (const float*)d_in[20];
    float* out = (float*)d_out;

    float* ws    = (float*)d_ws;
    float* adj2f = ws;                  // BNN
    float* Ebuf  = adj2f + BNN;         // BNN
    float* ATT   = Ebuf + BNN;          // BNN
    float* x     = ATT + BNN;           // BND
    float* h     = x + BND;             // BND
    float* hA    = h + BND;             // BND
    float* hp    = hA + BND;            // BND
    float* g1    = hp + BND;            // BND
    // total: 3*BNN + 5*BND floats = 147.7 MB
    // After the GAT loop, Ebuf is dead -> reuse as pooling partials (B*48*140 floats)
    float* part  = Ebuf;

    k_embed<<<(BND + 255) / 256, 256, 0, stream>>>(c_hs, Wemb, x);
    k_adj2<<<(BNN + 255) / 256, 256, 0, stream>>>(c_a2, valid, nat, mu, dev, adj2f);

    for (int l = 0; l < L; ++l) {
        const float* Wl  = gatW + (size_t)l * D * D;
        const float* Wbl = gatWb + (size_t)l * D;
        const float* Al  = gatA + (size_t)l * D * D;
        const float* gwl = gatgw + (size_t)l * 2 * D;
        const float* gbl = gatgb + l;

        k_linear140<<<(BND + 255) / 256, 256, 0, stream>>>(x, Wl, Wbl, h);
        k_linear140<<<(BND + 255) / 256, 256, 0, stream>>>(h, Al, nullptr, hA);
        k_e<<<dim3(N / 32, N / 32, B), 256, 0, stream>>>(h, hA, Ebuf);

        // gate 1: adj = c_adjs1
        k_softmax<<<dim3(N / 64, B), 256, 0, stream>>>(Ebuf, adj1, ATT);
        k_ath<<<dim3(N / 32, (D + 31) / 32, B), 256, 0, stream>>>(ATT, h, hp);
        k_gate<<<B * N, 64, 0, stream>>>(x, hp, gwl, gbl, g1, nullptr, 0);

        // gate 2: adj = adj2f; x = gate2 - gate1 (in place)
        k_softmax<<<dim3(N / 64, B), 256, 0, stream>>>(Ebuf, adj2f, ATT);
        k_ath<<<dim3(N / 32, (D + 31) / 32, B), 256, 0, stream>>>(ATT, h, hp);
        k_gate<<<B * N, 64, 0, stream>>>(x, hp, gwl, gbl, g1, x, 1);
    }

    // two-stage ragged pool, then MLP head
    k_pool<<<dim3(NCHUNK, B), 256, 0, stream>>>(x, nat, part);
    k_final<<<B, 256, 0, stream>>>(part, w0, b0, w1, b1, w2, b2, w3, b3, out);
}

// Round 2
// 2659.007 us; speedup vs baseline: 1.1751x; 1.1212x over previous
//
#include <hip/hip_runtime.h>

// Problem constants
constexpr int B   = 16;
constexpr int N   = 768;
constexpr int FIN = 56;
constexpr int D   = 140;
constexpr int L   = 4;
constexpr int DF  = 128;
constexpr int NN  = N * N;        // 589824
constexpr int BND = B * N * D;    // 1720320
constexpr int BNN = B * NN;       // 9437184

// pooling split
constexpr int PROWS  = 16;            // rows per pooling block
constexpr int NCHUNK = N / PROWS;     // 48 partials per batch

// k_e tiling
constexpr int KC = 70;                // K-chunk (140 = 2*70)

// ---------------------------------------------------------------------------
// K1: x = c_hs @ W_emb   [B*N,56] @ [56,140]
__global__ __launch_bounds__(256) void k_embed(const float* __restrict__ chs,
                                               const float* __restrict__ Wemb,
                                               float* __restrict__ x) {
    int idx = blockIdx.x * 256 + threadIdx.x;
    if (idx >= BND) return;
    int d  = idx % D;
    int bn = idx / D;
    const float* row = chs + bn * FIN;
    float acc = 0.f;
#pragma unroll 8
    for (int f = 0; f < FIN; ++f) acc += row[f] * Wemb[f * D + d];
    x[idx] = acc;
}

// ---------------------------------------------------------------------------
// K2: adj2 = formulate(c_adjs2)  (elementwise, mask from valid/num_atoms)
__global__ __launch_bounds__(256) void k_adj2(const float* __restrict__ a2,
                                              const int* __restrict__ valid,
                                              const int* __restrict__ natoms,
                                              const float* __restrict__ mu,
                                              const float* __restrict__ dev,
                                              float* __restrict__ out) {
    int idx = blockIdx.x * 256 + threadIdx.x;
    if (idx >= BNN) return;
    int b   = idx / NN;
    int rem = idx - b * NN;
    int i   = rem / N;
    int j   = rem - i * N;
    float a = a2[idx];
    int vi = valid[b * N + i];
    int vj = valid[b * N + j];
    int n  = natoms[b];
    bool mask = (vi && !vj && (j < n)) || (vj && !vi && (i < n));
    float dmu = a - mu[0];
    float g = (a <= 10.f) ? expf(-dmu * dmu / dev[0]) : 0.f;
    out[idx] = mask ? g : a;
}

// ---------------------------------------------------------------------------
// K3: out[bn,d] = in[bn,:] @ W[:,d] (+ bias)   — [B*N,140]@[140,140]
__global__ __launch_bounds__(256) void k_linear140(const float* __restrict__ in,
                                                   const float* __restrict__ W,
                                                   const float* __restrict__ bias,
                                                   float* __restrict__ out) {
    int idx = blockIdx.x * 256 + threadIdx.x;
    if (idx >= BND) return;
    int d  = idx % D;
    int bn = idx / D;
    const float* row = in + bn * D;
    float acc = bias ? bias[d] : 0.f;
#pragma unroll 4
    for (int k = 0; k < D; ++k) acc += row[k] * W[k * D + d];
    out[idx] = acc;
}

// ---------------------------------------------------------------------------
// K4: E[b,j,k] = hA[b,j,:]·h[b,k,:] + hA[b,k,:]·h[b,j,:]  (symmetric).
// 64x64 upper-triangle tiles, 4jx4k register micro-tile per thread.
// Transposed LDS (s[c][j], pad 68) -> both operand reads are float4,
// 2 ds_read_b128 per 16 FMAs = VALU-bound. K split in halves (KC=70), 38KB LDS.
__global__ __launch_bounds__(256) void k_e(const float* __restrict__ h,
                                           const float* __restrict__ hA,
                                           float* __restrict__ E) {
    int tj = blockIdx.x, tk = blockIdx.y, b = blockIdx.z;
    if (tj > tk) return;
    __shared__ float sJ[KC][68];   // transposed j-tile chunk
    __shared__ float sK[KC][68];   // transposed k-tile chunk
    int tid = threadIdx.x;
    int jg  = tid & 15;            // 16 j-groups x 4 j
    int kg  = tid >> 4;            // 16 k-groups x 4 k
    int cl  = tid & 63;            // staging: c-lane (coalesced)
    int jq  = tid >> 6;            // staging: row-group 0..3
    int j0 = tj * 64, k0 = tk * 64;
    const float* hb = h  + (size_t)b * N * D;
    const float* ab = hA + (size_t)b * N * D;

    float acc[4][4] = {};

    for (int r = 0; r < 4; ++r) {
        int ph = r >> 1;                  // 0: hA(j)·h(k), 1: h(j)·hA(k)
        int c0 = (r & 1) * KC;
        const float* uS = ph ? hb : ab;   // j-side source
        const float* vS = ph ? ab : hb;   // k-side source
        if (r) __syncthreads();
        // stage: global rows (coalesced in c) -> transposed LDS
        for (int jj = jq; jj < 64; jj += 4) {
            const float* ur = uS + (size_t)(j0 + jj) * D + c0;
            const float* vr = vS + (size_t)(k0 + jj) * D + c0;
            sJ[cl][jj] = ur[cl];
            sK[cl][jj] = vr[cl];
            if (cl < KC - 64) {
                sJ[cl + 64][jj] = ur[cl + 64];
                sK[cl + 64][jj] = vr[cl + 64];
            }
        }
        __syncthreads();
#pragma unroll 2
        for (int kk = 0; kk < KC; ++kk) {
            float4 ajv = *reinterpret_cast<const float4*>(&sJ[kk][jg * 4]);
            float4 akv = *reinterpret_cast<const float4*>(&sK[kk][kg * 4]);
            float aj[4] = {ajv.x, ajv.y, ajv.z, ajv.w};
            float ak[4] = {akv.x, akv.y, akv.z, akv.w};
#pragma unroll
            for (int i = 0; i < 4; ++i)
#pragma unroll
                for (int q = 0; q < 4; ++q) acc[i][q] += aj[i] * ak[q];
        }
    }

    float* Eb = E + (size_t)b * NN;
    int jb = j0 + jg * 4, kb = k0 + kg * 4;
#pragma unroll
    for (int i = 0; i < 4; ++i) {
        float4 v = {acc[i][0], acc[i][1], acc[i][2], acc[i][3]};
        *reinterpret_cast<float4*>(&Eb[(size_t)(jb + i) * N + kb]) = v;
    }
    // mirror: j-values per thread are contiguous -> also float4
#pragma unroll
    for (int q = 0; q < 4; ++q) {
        float4 v = {acc[0][q], acc[1][q], acc[2][q], acc[3][q]};
        *reinterpret_cast<float4*>(&Eb[(size_t)(kb + q) * N + jb]) = v;
    }
}

// ---------------------------------------------------------------------------
// K5: column softmax over axis j of masked E, times adj.
// ATT[b,j,k] = softmax_j( adj>0 ? E : -9e15 ) * adj
// Block: 64 columns x 16 j-slices (1024 thr) -> 3 waves/SIMD, 48-iter chains.
__global__ __launch_bounds__(1024) void k_softmax(const float* __restrict__ E,
                                                  const float* __restrict__ adj,
                                                  float* __restrict__ ATT) {
    int b    = blockIdx.y;
    int lane = threadIdx.x & 63;
    int js   = threadIdx.x >> 6;   // 0..15
    int k    = blockIdx.x * 64 + lane;
    const float* Eb = E   + (size_t)b * NN;
    const float* Ab = adj + (size_t)b * NN;
    float*       Tb = ATT + (size_t)b * NN;

    float m = -3.0e38f, s = 0.f;
    for (int j = js; j < N; j += 16) {
        float av = Ab[(size_t)j * N + k];
        float ev = Eb[(size_t)j * N + k];
        float x  = (av > 0.f) ? ev : -9e15f;
        float nm = fmaxf(m, x);
        s = s * __expf(m - nm) + __expf(x - nm);
        m = nm;
    }
    __shared__ float sm[16][64], ss[16][64];
    sm[js][lane] = m;
    ss[js][lane] = s;
    __syncthreads();
    if (js == 0) {
        float M = sm[0][lane], S = ss[0][lane];
#pragma unroll
        for (int q = 1; q < 16; ++q) {
            float m2 = sm[q][lane], s2 = ss[q][lane];
            float nm = fmaxf(M, m2);
            S = S * __expf(M - nm) + s2 * __expf(m2 - nm);
            M = nm;
        }
        sm[0][lane] = M;
        ss[0][lane] = 1.f / S;
    }
    __syncthreads();
    float M = sm[0][lane], invS = ss[0][lane];
    for (int j = js; j < N; j += 16) {
        float av = Ab[(size_t)j * N + k];
        float ev = Eb[(size_t)j * N + k];
        float x  = (av > 0.f) ? ev : -9e15f;
        Tb[(size_t)j * N + k] = __expf(x - M) * invS * av;
    }
}

// ---------------------------------------------------------------------------
// K6: hp = relu(ATT @ h)   [768,768]@[768,140], 32x32-d tiles
__global__ __launch_bounds__(256) void k_ath(const float* __restrict__ ATT,
                                             const float* __restrict__ h,
                                             float* __restrict__ hp) {
    int ti = blockIdx.x, td = blockIdx.y, b = blockIdx.z;
    __shared__ float sA[32][33];
    __shared__ float sH[32][33];
    int tid   = threadIdx.x;
    int col   = tid & 31;
    int rbase = tid >> 5;
    int i0 = ti * 32, d0 = td * 32;
    const float* Tb = ATT + (size_t)b * NN;
    const float* hb = h + (size_t)b * N * D;
    float acc[4] = {0.f, 0.f, 0.f, 0.f};
    int d = d0 + col;
    for (int jt = 0; jt < N / 32; ++jt) {
        int j0 = jt * 32;
#pragma unroll
        for (int q = 0; q < 4; ++q) {
            int r = rbase + q * 8;
            sA[r][col] = Tb[(size_t)(i0 + r) * N + (j0 + col)];
            sH[r][col] = (d < D) ? hb[(size_t)(j0 + r) * D + d] : 0.f;
        }
        __syncthreads();
#pragma unroll 8
        for (int jj = 0; jj < 32; ++jj) {
            float hv = sH[jj][col];
#pragma unroll
            for (int q = 0; q < 4; ++q) acc[q] += sA[rbase + q * 8][jj] * hv;
        }
        __syncthreads();
    }
    if (d < D) {
#pragma unroll
        for (int q = 0; q < 4; ++q) {
            int i = i0 + rbase + q * 8;
            hp[(size_t)b * N * D + (size_t)i * D + d] = fmaxf(acc[q], 0.f);
        }
    }
}

// ---------------------------------------------------------------------------
// K7: gate combine. mode 0: g1 = coeff*x+(1-coeff)*hp
//                   mode 1: x  = (coeff*x+(1-coeff)*hp) - g1   (in place)
__global__ __launch_bounds__(64) void k_gate(const float* __restrict__ x,
                                             const float* __restrict__ hp,
                                             const float* __restrict__ gw,
                                             const float* __restrict__ gb,
                                             float* __restrict__ g1,
                                             float* __restrict__ xout,
                                             int mode) {
    int row  = blockIdx.x;           // 0..B*N-1
    int lane = threadIdx.x;
    const float* xr = x  + (size_t)row * D;
    const float* hr = hp + (size_t)row * D;
    float part = 0.f;
    for (int d = lane; d < D; d += 64) part += xr[d] * gw[d] + hr[d] * gw[D + d];
#pragma unroll
    for (int off = 32; off; off >>= 1) part += __shfl_xor(part, off);
    float c = 1.f / (1.f + __expf(-(part + gb[0])));
    for (int d = lane; d < D; d += 64) {
        float v = c * xr[d] + (1.f - c) * hr[d];
        if (mode == 0) g1[(size_t)row * D + d] = v;
        else           xout[(size_t)row * D + d] = v - g1[(size_t)row * D + d];
    }
}

// ---------------------------------------------------------------------------
// K8a: parallel ragged sum-pool, stage 1.
__global__ __launch_bounds__(256) void k_pool(const float* __restrict__ x,
                                              const int* __restrict__ natoms,
                                              float* __restrict__ part) {
    int c = blockIdx.x;              // chunk
    int b = blockIdx.y;              // batch
    int tid = threadIdx.x;
    if (tid >= D) return;
    int n  = natoms[b];
    int r0 = c * PROWS;
    int r1 = min(r0 + PROWS, n);
    const float* xb = x + (size_t)b * N * D;
    float acc = 0.f;
    for (int r = r0; r < r1; ++r) acc += xb[(size_t)r * D + tid];
    part[((size_t)b * NCHUNK + c) * D + tid] = acc;
}

// ---------------------------------------------------------------------------
// K8b: combine partials + 4-layer MLP + sigmoid. One block per batch.
__global__ __launch_bounds__(256) void k_final(const float* __restrict__ part,
                                               const float* __restrict__ w0, const float* __restrict__ b0,
                                               const float* __restrict__ w1, const float* __restrict__ b1,
                                               const float* __restrict__ w2, const float* __restrict__ b2,
                                               const float* __restrict__ w3, const float* __restrict__ b3,
                                               float* __restrict__ out) {
    int b   = blockIdx.x;
    int tid = threadIdx.x;
    __shared__ float pred[D];
    __shared__ float h0[DF], h1[DF], h2[DF];
    if (tid < D) {
        float acc = 0.f;
        const float* pb = part + (size_t)b * NCHUNK * D;
#pragma unroll 8
        for (int c = 0; c < NCHUNK; ++c) acc += pb[(size_t)c * D + tid];
        pred[tid] = acc;
    }
    __syncthreads();
    if (tid < DF) {
        float acc = b0[tid];
#pragma unroll 4
        for (int i = 0; i < D; ++i) acc += pred[i] * w0[i * DF + tid];
        h0[tid] = fmaxf(acc, 0.f);
    }
    __syncthreads();
    if (tid < DF) {
        float acc = b1[tid];
#pragma unroll 4
        for (int i = 0; i < DF; ++i) acc += h0[i] * w1[i * DF + tid];
        h1[tid] = fmaxf(acc, 0.f);
    }
    __syncthreads();
    if (tid < DF) {
        float acc = b2[tid];
#pragma unroll 4
        for (int i = 0; i < DF; ++i) acc += h1[i] * w2[i * DF + tid];
        h2[tid] = fmaxf(acc, 0.f);
    }
    __syncthreads();
    if (tid == 0) {
        float acc = b3[0];
        for (int i = 0; i < DF; ++i) acc += h2[i] * w3[i];
        out[b] = 1.f / (1.f + expf(-acc));
    }
}

// ---------------------------------------------------------------------------
extern "C" void kernel_launch(void* const* d_in, const int* in_sizes, int n_in,
                              void* d_out, int out_size, void* d_ws, size_t ws_size,
                              hipStream_t stream) {
    const float* c_hs  = (const float*)d_in[0];
    const float* adj1  = (const float*)d_in[1];
    const float* c_a2  = (const float*)d_in[2];
    const int*   valid = (const int*)d_in[3];
    const int*   nat   = (const int*)d_in[4];
    const float* Wemb  = (const float*)d_in[5];
    const float* gatW  = (const float*)d_in[6];
    const float* gatWb = (const float*)d_in[7];
    const float* gatA  = (const float*)d_in[8];
    const float* gatgw = (const float*)d_in[9];
    const float* gatgb = (const float*)d_in[10];
    const float* w0 = (const float*)d_in[11];
    const float* b0 = (const float*)d_in[12];
    const float* w1 = (const float*)d_in[13];
    const float* b1 = (const float*)d_in[14];
    const float* w2 = (const float*)d_in[15];
    const float* b2 = (const float*)d_in[16];
    const float* w3 = (const float*)d_in[17];
    const float* b3 = (const float*)d_in[18];
    const float* mu  = (const float*)d_in[19];
    const float* dev = (const float*)d_in[20];
    float* out = (float*)d_out;

    float* ws    = (float*)d_ws;
    float* adj2f = ws;                  // BNN
    float* Ebuf  = adj2f + BNN;         // BNN
    float* ATT   = Ebuf + BNN;          // BNN
    float* x     = ATT + BNN;           // BND
    float* h     = x + BND;             // BND
    float* hA    = h + BND;             // BND
    float* hp    = hA + BND;            // BND
    float* g1    = hp + BND;            // BND
    // total: 3*BNN + 5*BND floats = 147.7 MB
    // After the GAT loop, Ebuf is dead -> reuse as pooling partials
    float* part  = Ebuf;

    k_embed<<<(BND + 255) / 256, 256, 0, stream>>>(c_hs, Wemb, x);
    k_adj2<<<(BNN + 255) / 256, 256, 0, stream>>>(c_a2, valid, nat, mu, dev, adj2f);

    for (int l = 0; l < L; ++l) {
        const float* Wl  = gatW + (size_t)l * D * D;
        const float* Wbl = gatWb + (size_t)l * D;
        const float* Al  = gatA + (size_t)l * D * D;
        const float* gwl = gatgw + (size_t)l * 2 * D;
        const float* gbl = gatgb + l;

        k_linear140<<<(BND + 255) / 256, 256, 0, stream>>>(x, Wl, Wbl, h);
        k_linear140<<<(BND + 255) / 256, 256, 0, stream>>>(h, Al, nullptr, hA);
        k_e<<<dim3(N / 64, N / 64, B), 256, 0, stream>>>(h, hA, Ebuf);

        // gate 1: adj = c_adjs1
        k_softmax<<<dim3(N / 64, B), 1024, 0, stream>>>(Ebuf, adj1, ATT);
        k_ath<<<dim3(N / 32, (D + 31) / 32, B), 256, 0, stream>>>(ATT, h, hp);
        k_gate<<<B * N, 64, 0, stream>>>(x, hp, gwl, gbl, g1, nullptr, 0);

        // gate 2: adj = adj2f; x = gate2 - gate1 (in place)
        k_softmax<<<dim3(N / 64, B), 1024, 0, stream>>>(Ebuf, adj2f, ATT);
        k_ath<<<dim3(N / 32, (D + 31) / 32, B), 256, 0, stream>>>(ATT, h, hp);
        k_gate<<<B * N, 64, 0, stream>>>(x, hp, gwl, gbl, g1, x, 1);
    }

    // two-stage ragged pool, then MLP head
    k_pool<<<dim3(NCHUNK, B), 256, 0, stream>>>(x, nat, part);
    k_final<<<B, 256, 0, stream>>>(part, w0, b0, w1, b1, w2, b2, w3, b3, out);
}

// Round 3
// 2447.605 us; speedup vs baseline: 1.2766x; 1.0864x over previous
//
#include <hip/hip_runtime.h>

// Problem constants
constexpr int B   = 16;
constexpr int N   = 768;
constexpr int FIN = 56;
constexpr int D   = 140;
constexpr int L   = 4;
constexpr int DF  = 128;
constexpr int NN  = N * N;        // 589824
constexpr int BND = B * N * D;    // 1720320
constexpr int BNN = B * NN;       // 9437184

// pooling split
constexpr int PROWS  = 16;            // rows per pooling block
constexpr int NCHUNK = N / PROWS;     // 48 partials per batch

// k_e tiling
constexpr int KC = 70;                // K-chunk (140 = 2*70)

// k_ath tiling
constexpr int DT = 48;                // d-tile (140 -> 3 tiles of 48, pad to 144)

// ---------------------------------------------------------------------------
// K1: x = c_hs @ W_emb   [B*N,56] @ [56,140]
__global__ __launch_bounds__(256) void k_embed(const float* __restrict__ chs,
                                               const float* __restrict__ Wemb,
                                               float* __restrict__ x) {
    int idx = blockIdx.x * 256 + threadIdx.x;
    if (idx >= BND) return;
    int d  = idx % D;
    int bn = idx / D;
    const float* row = chs + bn * FIN;
    float acc = 0.f;
#pragma unroll 8
    for (int f = 0; f < FIN; ++f) acc += row[f] * Wemb[f * D + d];
    x[idx] = acc;
}

// ---------------------------------------------------------------------------
// K2: adj2 = formulate(c_adjs2)  (elementwise, mask from valid/num_atoms)
__global__ __launch_bounds__(256) void k_adj2(const float* __restrict__ a2,
                                              const int* __restrict__ valid,
                                              const int* __restrict__ natoms,
                                              const float* __restrict__ mu,
                                              const float* __restrict__ dev,
                                              float* __restrict__ out) {
    int idx = blockIdx.x * 256 + threadIdx.x;
    if (idx >= BNN) return;
    int b   = idx / NN;
    int rem = idx - b * NN;
    int i   = rem / N;
    int j   = rem - i * N;
    float a = a2[idx];
    int vi = valid[b * N + i];
    int vj = valid[b * N + j];
    int n  = natoms[b];
    bool mask = (vi && !vj && (j < n)) || (vj && !vi && (i < n));
    float dmu = a - mu[0];
    float g = (a <= 10.f) ? expf(-dmu * dmu / dev[0]) : 0.f;
    out[idx] = mask ? g : a;
}

// ---------------------------------------------------------------------------
// K3: out[bn,d] = in[bn,:] @ W[:,d] (+ bias)   — [B*N,140]@[140,140]
__global__ __launch_bounds__(256) void k_linear140(const float* __restrict__ in,
                                                   const float* __restrict__ W,
                                                   const float* __restrict__ bias,
                                                   float* __restrict__ out) {
    int idx = blockIdx.x * 256 + threadIdx.x;
    if (idx >= BND) return;
    int d  = idx % D;
    int bn = idx / D;
    const float* row = in + bn * D;
    float acc = bias ? bias[d] : 0.f;
#pragma unroll 4
    for (int k = 0; k < D; ++k) acc += row[k] * W[k * D + d];
    out[idx] = acc;
}

// ---------------------------------------------------------------------------
// K4: E[b,j,k] = hA[b,j,:]·h[b,k,:] + hA[b,k,:]·h[b,j,:]  (symmetric).
// 64x64 upper-triangle tiles, 4jx4k register micro-tile per thread.
__global__ __launch_bounds__(256) void k_e(const float* __restrict__ h,
                                           const float* __restrict__ hA,
                                           float* __restrict__ E) {
    int tj = blockIdx.x, tk = blockIdx.y, b = blockIdx.z;
    if (tj > tk) return;
    __shared__ float sJ[KC][68];   // transposed j-tile chunk
    __shared__ float sK[KC][68];   // transposed k-tile chunk
    int tid = threadIdx.x;
    int jg  = tid & 15;            // 16 j-groups x 4 j
    int kg  = tid >> 4;            // 16 k-groups x 4 k
    int cl  = tid & 63;            // staging: c-lane (coalesced)
    int jq  = tid >> 6;            // staging: row-group 0..3
    int j0 = tj * 64, k0 = tk * 64;
    const float* hb = h  + (size_t)b * N * D;
    const float* ab = hA + (size_t)b * N * D;

    float acc[4][4] = {};

    for (int r = 0; r < 4; ++r) {
        int ph = r >> 1;                  // 0: hA(j)·h(k), 1: h(j)·hA(k)
        int c0 = (r & 1) * KC;
        const float* uS = ph ? hb : ab;   // j-side source
        const float* vS = ph ? ab : hb;   // k-side source
        if (r) __syncthreads();
        // stage: global rows (coalesced in c) -> transposed LDS
        for (int jj = jq; jj < 64; jj += 4) {
            const float* ur = uS + (size_t)(j0 + jj) * D + c0;
            const float* vr = vS + (size_t)(k0 + jj) * D + c0;
            sJ[cl][jj] = ur[cl];
            sK[cl][jj] = vr[cl];
            if (cl < KC - 64) {
                sJ[cl + 64][jj] = ur[cl + 64];
                sK[cl + 64][jj] = vr[cl + 64];
            }
        }
        __syncthreads();
#pragma unroll 2
        for (int kk = 0; kk < KC; ++kk) {
            float4 ajv = *reinterpret_cast<const float4*>(&sJ[kk][jg * 4]);
            float4 akv = *reinterpret_cast<const float4*>(&sK[kk][kg * 4]);
            float aj[4] = {ajv.x, ajv.y, ajv.z, ajv.w};
            float ak[4] = {akv.x, akv.y, akv.z, akv.w};
#pragma unroll
            for (int i = 0; i < 4; ++i)
#pragma unroll
                for (int q = 0; q < 4; ++q) acc[i][q] += aj[i] * ak[q];
        }
    }

    float* Eb = E + (size_t)b * NN;
    int jb = j0 + jg * 4, kb = k0 + kg * 4;
#pragma unroll
    for (int i = 0; i < 4; ++i) {
        float4 v = {acc[i][0], acc[i][1], acc[i][2], acc[i][3]};
        *reinterpret_cast<float4*>(&Eb[(size_t)(jb + i) * N + kb]) = v;
    }
    // mirror: j-values per thread are contiguous -> also float4
#pragma unroll
    for (int q = 0; q < 4; ++q) {
        float4 v = {acc[0][q], acc[1][q], acc[2][q], acc[3][q]};
        *reinterpret_cast<float4*>(&Eb[(size_t)(kb + q) * N + jb]) = v;
    }
}

// ---------------------------------------------------------------------------
// K5: column softmax over axis j of masked E, times adj.
__global__ __launch_bounds__(1024) void k_softmax(const float* __restrict__ E,
                                                  const float* __restrict__ adj,
                                                  float* __restrict__ ATT) {
    int b    = blockIdx.y;
    int lane = threadIdx.x & 63;
    int js   = threadIdx.x >> 6;   // 0..15
    int k    = blockIdx.x * 64 + lane;
    const float* Eb = E   + (size_t)b * NN;
    const float* Ab = adj + (size_t)b * NN;
    float*       Tb = ATT + (size_t)b * NN;

    float m = -3.0e38f, s = 0.f;
    for (int j = js; j < N; j += 16) {
        float av = Ab[(size_t)j * N + k];
        float ev = Eb[(size_t)j * N + k];
        float x  = (av > 0.f) ? ev : -9e15f;
        float nm = fmaxf(m, x);
        s = s * __expf(m - nm) + __expf(x - nm);
        m = nm;
    }
    __shared__ float sm[16][64], ss[16][64];
    sm[js][lane] = m;
    ss[js][lane] = s;
    __syncthreads();
    if (js == 0) {
        float M = sm[0][lane], S = ss[0][lane];
#pragma unroll
        for (int q = 1; q < 16; ++q) {
            float m2 = sm[q][lane], s2 = ss[q][lane];
            float nm = fmaxf(M, m2);
            S = S * __expf(M - nm) + s2 * __expf(m2 - nm);
            M = nm;
        }
        sm[0][lane] = M;
        ss[0][lane] = 1.f / S;
    }
    __syncthreads();
    float M = sm[0][lane], invS = ss[0][lane];
    for (int j = js; j < N; j += 16) {
        float av = Ab[(size_t)j * N + k];
        float ev = Eb[(size_t)j * N + k];
        float x  = (av > 0.f) ? ev : -9e15f;
        Tb[(size_t)j * N + k] = __expf(x - M) * invS * av;
    }
}

// ---------------------------------------------------------------------------
// K6: hp = relu(ATT @ h)   [768,768]@[768,140] per batch.
// k_e-style register blocking: 64 i-rows x 48 d-cols per block, 192 threads,
// 4i x 4d micro-tile. sA transposed [j][i] (pad 68) so the i-fragment is a
// float4; sH natural [j][d] (pad 52). Inner loop: 2 ds_read_b128 + 16 FMA.
__global__ __launch_bounds__(192) void k_ath(const float* __restrict__ ATT,
                                             const float* __restrict__ h,
                                             float* __restrict__ hp) {
    int ti = blockIdx.x, td = blockIdx.y, b = blockIdx.z;
    __shared__ float sA[64][68];   // [j][i] transposed ATT tile
    __shared__ float sH[64][52];   // [j][d] h tile
    int tid = threadIdx.x;
    int ig  = tid & 15;            // 16 groups x 4 i
    int dg  = tid >> 4;            // 12 groups x 4 d
    int i0  = ti * 64, d0 = td * DT;
    const float* Tb = ATT + (size_t)b * NN;
    const float* hb = h   + (size_t)b * N * D;

    // staging indices for sH: 48 d-lanes x 4 j-rows
    int sd = tid % DT;             // 0..47
    int sj = tid / DT;             // 0..3
    int dd = d0 + sd;
    bool dok = (dd < D);

    float acc[4][4] = {};

    for (int jt = 0; jt < N / 64; ++jt) {
        int j0 = jt * 64;
        if (jt) __syncthreads();
        // stage sA: ATT[i0+i][j0+j] -> sA[j][i]  (coalesced global read in j)
        for (int idx = tid; idx < 64 * 64; idx += 192) {
            int i = idx >> 6, j = idx & 63;
            sA[j][i] = Tb[(size_t)(i0 + i) * N + (j0 + j)];
        }
        // stage sH: h[j0+j][d0+sd] -> sH[j][sd]  (coalesced in d)
        for (int j = sj; j < 64; j += 4) {
            sH[j][sd] = dok ? hb[(size_t)(j0 + j) * D + dd] : 0.f;
        }
        __syncthreads();
#pragma unroll 4
        for (int kk = 0; kk < 64; ++kk) {
            float4 av = *reinterpret_cast<const float4*>(&sA[kk][ig * 4]);
            float4 hv = *reinterpret_cast<const float4*>(&sH[kk][dg * 4]);
            float ai[4] = {av.x, av.y, av.z, av.w};
            float hd[4] = {hv.x, hv.y, hv.z, hv.w};
#pragma unroll
            for (int i = 0; i < 4; ++i)
#pragma unroll
                for (int q = 0; q < 4; ++q) acc[i][q] += ai[i] * hd[q];
        }
    }

    int dw = d0 + dg * 4;
    if (dw < D) {
        float* hb_out = hp + (size_t)b * N * D;
#pragma unroll
        for (int i = 0; i < 4; ++i) {
            int row = i0 + ig * 4 + i;
            float4 v = {fmaxf(acc[i][0], 0.f), fmaxf(acc[i][1], 0.f),
                        fmaxf(acc[i][2], 0.f), fmaxf(acc[i][3], 0.f)};
            *reinterpret_cast<float4*>(&hb_out[(size_t)row * D + dw]) = v;
        }
    }
}

// ---------------------------------------------------------------------------
// K7: gate combine. mode 0: g1 = coeff*x+(1-coeff)*hp
//                   mode 1: x  = (coeff*x+(1-coeff)*hp) - g1   (in place)
__global__ __launch_bounds__(64) void k_gate(const float* __restrict__ x,
                                             const float* __restrict__ hp,
                                             const float* __restrict__ gw,
                                             const float* __restrict__ gb,
                                             float* __restrict__ g1,
                                             float* __restrict__ xout,
                                             int mode) {
    int row  = blockIdx.x;           // 0..B*N-1
    int lane = threadIdx.x;
    const float* xr = x  + (size_t)row * D;
    const float* hr = hp + (size_t)row * D;
    float part = 0.f;
    for (int d = lane; d < D; d += 64) part += xr[d] * gw[d] + hr[d] * gw[D + d];
#pragma unroll
    for (int off = 32; off; off >>= 1) part += __shfl_xor(part, off);
    float c = 1.f / (1.f + __expf(-(part + gb[0])));
    for (int d = lane; d < D; d += 64) {
        float v = c * xr[d] + (1.f - c) * hr[d];
        if (mode == 0) g1[(size_t)row * D + d] = v;
        else           xout[(size_t)row * D + d] = v - g1[(size_t)row * D + d];
    }
}

// ---------------------------------------------------------------------------
// K8a: parallel ragged sum-pool, stage 1.
__global__ __launch_bounds__(256) void k_pool(const float* __restrict__ x,
                                              const int* __restrict__ natoms,
                                              float* __restrict__ part) {
    int c = blockIdx.x;              // chunk
    int b = blockIdx.y;              // batch
    int tid = threadIdx.x;
    if (tid >= D) return;
    int n  = natoms[b];
    int r0 = c * PROWS;
    int r1 = min(r0 + PROWS, n);
    const float* xb = x + (size_t)b * N * D;
    float acc = 0.f;
    for (int r = r0; r < r1; ++r) acc += xb[(size_t)r * D + tid];
    part[((size_t)b * NCHUNK + c) * D + tid] = acc;
}

// ---------------------------------------------------------------------------
// K8b: combine partials + 4-layer MLP + sigmoid. One block per batch.
__global__ __launch_bounds__(256) void k_final(const float* __restrict__ part,
                                               const float* __restrict__ w0, const float* __restrict__ b0,
                                               const float* __restrict__ w1, const float* __restrict__ b1,
                                               const float* __restrict__ w2, const float* __restrict__ b2,
                                               const float* __restrict__ w3, const float* __restrict__ b3,
                                               float* __restrict__ out) {
    int b   = blockIdx.x;
    int tid = threadIdx.x;
    __shared__ float pred[D];
    __shared__ float h0[DF], h1[DF], h2[DF];
    if (tid < D) {
        float acc = 0.f;
        const float* pb = part + (size_t)b * NCHUNK * D;
#pragma unroll 8
        for (int c = 0; c < NCHUNK; ++c) acc += pb[(size_t)c * D + tid];
        pred[tid] = acc;
    }
    __syncthreads();
    if (tid < DF) {
        float acc = b0[tid];
#pragma unroll 4
        for (int i = 0; i < D; ++i) acc += pred[i] * w0[i * DF + tid];
        h0[tid] = fmaxf(acc, 0.f);
    }
    __syncthreads();
    if (tid < DF) {
        float acc = b1[tid];
#pragma unroll 4
        for (int i = 0; i < DF; ++i) acc += h0[i] * w1[i * DF + tid];
        h1[tid] = fmaxf(acc, 0.f);
    }
    __syncthreads();
    if (tid < DF) {
        float acc = b2[tid];
#pragma unroll 4
        for (int i = 0; i < DF; ++i) acc += h1[i] * w2[i * DF + tid];
        h2[tid] = fmaxf(acc, 0.f);
    }
    __syncthreads();
    if (tid == 0) {
        float acc = b3[0];
        for (int i = 0; i < DF; ++i) acc += h2[i] * w3[i];
        out[b] = 1.f / (1.f + expf(-acc));
    }
}

// ---------------------------------------------------------------------------
extern "C" void kernel_launch(void* const* d_in, const int* in_sizes, int n_in,
                              void* d_out, int out_size, void* d_ws, size_t ws_size,
                              hipStream_t stream) {
    const float* c_hs  = (const float*)d_in[0];
    const float* adj1  = (const float*)d_in[1];
    const float* c_a2  = (const float*)d_in[2];
    const int*   valid = (const int*)d_in[3];
    const int*   nat   = (const int*)d_in[4];
    const float* Wemb  = (const float*)d_in[5];
    const float* gatW  = (const float*)d_in[6];
    const float* gatWb = (const float*)d_in[7];
    const float* gatA  = (const float*)d_in[8];
    const float* gatgw = (const float*)d_in[9];
    const float* gatgb = (const float*)d_in[10];
    const float* w0 = (const float*)d_in[11];
    const float* b0 = (const float*)d_in[12];
    const float* w1 = (const float*)d_in[13];
    const float* b1 = (const float*)d_in[14];
    const float* w2 = (const float*)d_in[15];
    const float* b2 = (const float*)d_in[16];
    const float* w3 = (const float*)d_in[17];
    const float* b3 = (const float*)d_in[18];
    const float* mu  = (const float*)d_in[19];
    const float* dev = (const float*)d_in[20];
    float* out = (float*)d_out;

    float* ws    = (float*)d_ws;
    float* adj2f = ws;                  // BNN
    float* Ebuf  = adj2f + BNN;         // BNN
    float* ATT   = Ebuf + BNN;          // BNN
    float* x     = ATT + BNN;           // BND
    float* h     = x + BND;             // BND
    float* hA    = h + BND;             // BND
    float* hp    = hA + BND;            // BND
    float* g1    = hp + BND;            // BND
    // total: 3*BNN + 5*BND floats = 147.7 MB
    // After the GAT loop, Ebuf is dead -> reuse as pooling partials
    float* part  = Ebuf;

    k_embed<<<(BND + 255) / 256, 256, 0, stream>>>(c_hs, Wemb, x);
    k_adj2<<<(BNN + 255) / 256, 256, 0, stream>>>(c_a2, valid, nat, mu, dev, adj2f);

    for (int l = 0; l < L; ++l) {
        const float* Wl  = gatW + (size_t)l * D * D;
        const float* Wbl = gatWb + (size_t)l * D;
        const float* Al  = gatA + (size_t)l * D * D;
        const float* gwl = gatgw + (size_t)l * 2 * D;
        const float* gbl = gatgb + l;

        k_linear140<<<(BND + 255) / 256, 256, 0, stream>>>(x, Wl, Wbl, h);
        k_linear140<<<(BND + 255) / 256, 256, 0, stream>>>(h, Al, nullptr, hA);
        k_e<<<dim3(N / 64, N / 64, B), 256, 0, stream>>>(h, hA, Ebuf);

        // gate 1: adj = c_adjs1
        k_softmax<<<dim3(N / 64, B), 1024, 0, stream>>>(Ebuf, adj1, ATT);
        k_ath<<<dim3(N / 64, 3, B), 192, 0, stream>>>(ATT, h, hp);
        k_gate<<<B * N, 64, 0, stream>>>(x, hp, gwl, gbl, g1, nullptr, 0);

        // gate 2: adj = adj2f; x = gate2 - gate1 (in place)
        k_softmax<<<dim3(N / 64, B), 1024, 0, stream>>>(Ebuf, adj2f, ATT);
        k_ath<<<dim3(N / 64, 3, B), 192, 0, stream>>>(ATT, h, hp);
        k_gate<<<B * N, 64, 0, stream>>>(x, hp, gwl, gbl, g1, x, 1);
    }

    // two-stage ragged pool, then MLP head
    k_pool<<<dim3(NCHUNK, B), 256, 0, stream>>>(x, nat, part);
    k_final<<<B, 256, 0, stream>>>(part, w0, b0, w1, b1, w2, b2, w3, b3, out);
}

// Round 4
// 2061.889 us; speedup vs baseline: 1.5154x; 1.1871x over previous
//
#include <hip/hip_runtime.h>

// Problem constants
constexpr int B   = 16;
constexpr int N   = 768;
constexpr int FIN = 56;
constexpr int D   = 140;
constexpr int L   = 4;
constexpr int DF  = 128;
constexpr int NN  = N * N;        // 589824
constexpr int BND = B * N * D;    // 1720320
constexpr int BNN = B * NN;       // 9437184

// pooling split
constexpr int PROWS  = 16;            // rows per pooling block
constexpr int NCHUNK = N / PROWS;     // 48 partials per batch

// k_e tiling
constexpr int KC = 70;                // K-chunk (140 = 2*70)

// k_ath tiling
constexpr int DT = 48;                // d-tile (140 -> 3 tiles of 48, pad to 144)
constexpr int JSPLIT = 2;             // j-halves -> partials in hp / hA

// ---------------------------------------------------------------------------
// K1: x = c_hs @ W_emb   [B*N,56] @ [56,140]
__global__ __launch_bounds__(256) void k_embed(const float* __restrict__ chs,
                                               const float* __restrict__ Wemb,
                                               float* __restrict__ x) {
    int idx = blockIdx.x * 256 + threadIdx.x;
    if (idx >= BND) return;
    int d  = idx % D;
    int bn = idx / D;
    const float* row = chs + bn * FIN;
    float acc = 0.f;
#pragma unroll 8
    for (int f = 0; f < FIN; ++f) acc += row[f] * Wemb[f * D + d];
    x[idx] = acc;
}

// ---------------------------------------------------------------------------
// K2: adj2 = formulate(c_adjs2)  (elementwise, mask from valid/num_atoms)
__global__ __launch_bounds__(256) void k_adj2(const float* __restrict__ a2,
                                              const int* __restrict__ valid,
                                              const int* __restrict__ natoms,
                                              const float* __restrict__ mu,
                                              const float* __restrict__ dev,
                                              float* __restrict__ out) {
    int idx = blockIdx.x * 256 + threadIdx.x;
    if (idx >= BNN) return;
    int b   = idx / NN;
    int rem = idx - b * NN;
    int i   = rem / N;
    int j   = rem - i * N;
    float a = a2[idx];
    int vi = valid[b * N + i];
    int vj = valid[b * N + j];
    int n  = natoms[b];
    bool mask = (vi && !vj && (j < n)) || (vj && !vi && (i < n));
    float dmu = a - mu[0];
    float g = (a <= 10.f) ? expf(-dmu * dmu / dev[0]) : 0.f;
    out[idx] = mask ? g : a;
}

// ---------------------------------------------------------------------------
// K3: out[bn,d] = in[bn,:] @ W[:,d] (+ bias)   — [B*N,140]@[140,140]
__global__ __launch_bounds__(256) void k_linear140(const float* __restrict__ in,
                                                   const float* __restrict__ W,
                                                   const float* __restrict__ bias,
                                                   float* __restrict__ out) {
    int idx = blockIdx.x * 256 + threadIdx.x;
    if (idx >= BND) return;
    int d  = idx % D;
    int bn = idx / D;
    const float* row = in + bn * D;
    float acc = bias ? bias[d] : 0.f;
#pragma unroll 4
    for (int k = 0; k < D; ++k) acc += row[k] * W[k * D + d];
    out[idx] = acc;
}

// ---------------------------------------------------------------------------
// K4: E[b,j,k] = hA[b,j,:]·h[b,k,:] + hA[b,k,:]·h[b,j,:]  (symmetric).
// 64x64 upper-triangle tiles, 4jx4k register micro-tile per thread.
__global__ __launch_bounds__(256) void k_e(const float* __restrict__ h,
                                           const float* __restrict__ hA,
                                           float* __restrict__ E) {
    int tj = blockIdx.x, tk = blockIdx.y, b = blockIdx.z;
    if (tj > tk) return;
    __shared__ float sJ[KC][68];   // transposed j-tile chunk
    __shared__ float sK[KC][68];   // transposed k-tile chunk
    int tid = threadIdx.x;
    int jg  = tid & 15;            // 16 j-groups x 4 j
    int kg  = tid >> 4;            // 16 k-groups x 4 k
    int cl  = tid & 63;            // staging: c-lane (coalesced)
    int jq  = tid >> 6;            // staging: row-group 0..3
    int j0 = tj * 64, k0 = tk * 64;
    const float* hb = h  + (size_t)b * N * D;
    const float* ab = hA + (size_t)b * N * D;

    float acc[4][4] = {};

    for (int r = 0; r < 4; ++r) {
        int ph = r >> 1;                  // 0: hA(j)·h(k), 1: h(j)·hA(k)
        int c0 = (r & 1) * KC;
        const float* uS = ph ? hb : ab;   // j-side source
        const float* vS = ph ? ab : hb;   // k-side source
        if (r) __syncthreads();
        // stage: global rows (coalesced in c) -> transposed LDS
        for (int jj = jq; jj < 64; jj += 4) {
            const float* ur = uS + (size_t)(j0 + jj) * D + c0;
            const float* vr = vS + (size_t)(k0 + jj) * D + c0;
            sJ[cl][jj] = ur[cl];
            sK[cl][jj] = vr[cl];
            if (cl < KC - 64) {
                sJ[cl + 64][jj] = ur[cl + 64];
                sK[cl + 64][jj] = vr[cl + 64];
            }
        }
        __syncthreads();
#pragma unroll 2
        for (int kk = 0; kk < KC; ++kk) {
            float4 ajv = *reinterpret_cast<const float4*>(&sJ[kk][jg * 4]);
            float4 akv = *reinterpret_cast<const float4*>(&sK[kk][kg * 4]);
            float aj[4] = {ajv.x, ajv.y, ajv.z, ajv.w};
            float ak[4] = {akv.x, akv.y, akv.z, akv.w};
#pragma unroll
            for (int i = 0; i < 4; ++i)
#pragma unroll
                for (int q = 0; q < 4; ++q) acc[i][q] += aj[i] * ak[q];
        }
    }

    float* Eb = E + (size_t)b * NN;
    int jb = j0 + jg * 4, kb = k0 + kg * 4;
#pragma unroll
    for (int i = 0; i < 4; ++i) {
        float4 v = {acc[i][0], acc[i][1], acc[i][2], acc[i][3]};
        *reinterpret_cast<float4*>(&Eb[(size_t)(jb + i) * N + kb]) = v;
    }
    // mirror: j-values per thread are contiguous -> also float4
#pragma unroll
    for (int q = 0; q < 4; ++q) {
        float4 v = {acc[0][q], acc[1][q], acc[2][q], acc[3][q]};
        *reinterpret_cast<float4*>(&Eb[(size_t)(kb + q) * N + jb]) = v;
    }
}

// ---------------------------------------------------------------------------
// K5: column softmax over axis j of masked E, times adj.
__global__ __launch_bounds__(1024) void k_softmax(const float* __restrict__ E,
                                                  const float* __restrict__ adj,
                                                  float* __restrict__ ATT) {
    int b    = blockIdx.y;
    int lane = threadIdx.x & 63;
    int js   = threadIdx.x >> 6;   // 0..15
    int k    = blockIdx.x * 64 + lane;
    const float* Eb = E   + (size_t)b * NN;
    const float* Ab = adj + (size_t)b * NN;
    float*       Tb = ATT + (size_t)b * NN;

    float m = -3.0e38f, s = 0.f;
    for (int j = js; j < N; j += 16) {
        float av = Ab[(size_t)j * N + k];
        float ev = Eb[(size_t)j * N + k];
        float x  = (av > 0.f) ? ev : -9e15f;
        float nm = fmaxf(m, x);
        s = s * __expf(m - nm) + __expf(x - nm);
        m = nm;
    }
    __shared__ float sm[16][64], ss[16][64];
    sm[js][lane] = m;
    ss[js][lane] = s;
    __syncthreads();
    if (js == 0) {
        float M = sm[0][lane], S = ss[0][lane];
#pragma unroll
        for (int q = 1; q < 16; ++q) {
            float m2 = sm[q][lane], s2 = ss[q][lane];
            float nm = fmaxf(M, m2);
            S = S * __expf(M - nm) + s2 * __expf(m2 - nm);
            M = nm;
        }
        sm[0][lane] = M;
        ss[0][lane] = 1.f / S;
    }
    __syncthreads();
    float M = sm[0][lane], invS = ss[0][lane];
    for (int j = js; j < N; j += 16) {
        float av = Ab[(size_t)j * N + k];
        float ev = Eb[(size_t)j * N + k];
        float x  = (av > 0.f) ? ev : -9e15f;
        Tb[(size_t)j * N + k] = __expf(x - M) * invS * av;
    }
}

// ---------------------------------------------------------------------------
// K6: partial of ATT @ h over half the j-range (NO relu here).
// js = blockIdx.z&1 selects j-tiles [js*6, js*6+6); partial -> pA (js=0) or
// pB (js=1, reusing the dead hA buffer). k_gate does relu(pA+pB).
// 64i x 48d per block, 192 threads, 4ix4d register micro-tile; grid 1152
// blocks -> ~4.5 blocks/CU (LDS 30.7KB allows 5) -> ~42% occupancy.
__global__ __launch_bounds__(192) void k_ath(const float* __restrict__ ATT,
                                             const float* __restrict__ h,
                                             float* __restrict__ pA,
                                             float* __restrict__ pB) {
    int ti = blockIdx.x, td = blockIdx.y;
    int bz = blockIdx.z;
    int b  = bz >> 1;
    int js = bz & 1;
    __shared__ float sA[64][68];   // [j][i] transposed ATT tile
    __shared__ float sH[64][52];   // [j][d] h tile
    int tid = threadIdx.x;
    int ig  = tid & 15;            // 16 groups x 4 i
    int dg  = tid >> 4;            // 12 groups x 4 d
    int i0  = ti * 64, d0 = td * DT;
    const float* Tb = ATT + (size_t)b * NN;
    const float* hb = h   + (size_t)b * N * D;

    // staging indices for sH: 48 d-lanes x 4 j-rows
    int sd = tid % DT;             // 0..47
    int sj = tid / DT;             // 0..3
    int dd = d0 + sd;
    bool dok = (dd < D);

    float acc[4][4] = {};

    int jt0 = js * (N / 64 / JSPLIT);
    int jt1 = jt0 + (N / 64 / JSPLIT);
    for (int jt = jt0; jt < jt1; ++jt) {
        int j0 = jt * 64;
        if (jt != jt0) __syncthreads();
        // stage sA: ATT[i0+i][j0+j] -> sA[j][i]  (coalesced global read in j)
        for (int idx = tid; idx < 64 * 64; idx += 192) {
            int i = idx >> 6, j = idx & 63;
            sA[j][i] = Tb[(size_t)(i0 + i) * N + (j0 + j)];
        }
        // stage sH: h[j0+j][d0+sd] -> sH[j][sd]  (coalesced in d)
        for (int j = sj; j < 64; j += 4) {
            sH[j][sd] = dok ? hb[(size_t)(j0 + j) * D + dd] : 0.f;
        }
        __syncthreads();
#pragma unroll 4
        for (int kk = 0; kk < 64; ++kk) {
            float4 av = *reinterpret_cast<const float4*>(&sA[kk][ig * 4]);
            float4 hv = *reinterpret_cast<const float4*>(&sH[kk][dg * 4]);
            float ai[4] = {av.x, av.y, av.z, av.w};
            float hd[4] = {hv.x, hv.y, hv.z, hv.w};
#pragma unroll
            for (int i = 0; i < 4; ++i)
#pragma unroll
                for (int q = 0; q < 4; ++q) acc[i][q] += ai[i] * hd[q];
        }
    }

    int dw = d0 + dg * 4;
    if (dw < D) {
        float* dst = (js ? pB : pA) + (size_t)b * N * D;
#pragma unroll
        for (int i = 0; i < 4; ++i) {
            int row = i0 + ig * 4 + i;
            float4 v = {acc[i][0], acc[i][1], acc[i][2], acc[i][3]};
            *reinterpret_cast<float4*>(&dst[(size_t)row * D + dw]) = v;
        }
    }
}

// ---------------------------------------------------------------------------
// K7: gate combine; hp = relu(pA + pB) computed on the fly.
// mode 0: g1 = coeff*x+(1-coeff)*hp
// mode 1: x  = (coeff*x+(1-coeff)*hp) - g1   (in place)
__global__ __launch_bounds__(64) void k_gate(const float* __restrict__ x,
                                             const float* __restrict__ pA,
                                             const float* __restrict__ pB,
                                             const float* __restrict__ gw,
                                             const float* __restrict__ gb,
                                             float* __restrict__ g1,
                                             float* __restrict__ xout,
                                             int mode) {
    int row  = blockIdx.x;           // 0..B*N-1
    int lane = threadIdx.x;
    const float* xr = x  + (size_t)row * D;
    const float* pa = pA + (size_t)row * D;
    const float* pb = pB + (size_t)row * D;
    float xv[3], hv[3];
    float part = 0.f;
#pragma unroll
    for (int q = 0; q < 3; ++q) {
        int d = lane + q * 64;
        xv[q] = 0.f; hv[q] = 0.f;
        if (d < D) {
            xv[q] = xr[d];
            hv[q] = fmaxf(pa[d] + pb[d], 0.f);
            part += xv[q] * gw[d] + hv[q] * gw[D + d];
        }
    }
#pragma unroll
    for (int off = 32; off; off >>= 1) part += __shfl_xor(part, off);
    float c = 1.f / (1.f + __expf(-(part + gb[0])));
#pragma unroll
    for (int q = 0; q < 3; ++q) {
        int d = lane + q * 64;
        if (d < D) {
            float v = c * xv[q] + (1.f - c) * hv[q];
            if (mode == 0) g1[(size_t)row * D + d] = v;
            else           xout[(size_t)row * D + d] = v - g1[(size_t)row * D + d];
        }
    }
}

// ---------------------------------------------------------------------------
// K8a: parallel ragged sum-pool, stage 1.
__global__ __launch_bounds__(256) void k_pool(const float* __restrict__ x,
                                              const int* __restrict__ natoms,
                                              float* __restrict__ part) {
    int c = blockIdx.x;              // chunk
    int b = blockIdx.y;              // batch
    int tid = threadIdx.x;
    if (tid >= D) return;
    int n  = natoms[b];
    int r0 = c * PROWS;
    int r1 = min(r0 + PROWS, n);
    const float* xb = x + (size_t)b * N * D;
    float acc = 0.f;
    for (int r = r0; r < r1; ++r) acc += xb[(size_t)r * D + tid];
    part[((size_t)b * NCHUNK + c) * D + tid] = acc;
}

// ---------------------------------------------------------------------------
// K8b: combine partials + 4-layer MLP + sigmoid. One block per batch.
__global__ __launch_bounds__(256) void k_final(const float* __restrict__ part,
                                               const float* __restrict__ w0, const float* __restrict__ b0,
                                               const float* __restrict__ w1, const float* __restrict__ b1,
                                               const float* __restrict__ w2, const float* __restrict__ b2,
                                               const float* __restrict__ w3, const float* __restrict__ b3,
                                               float* __restrict__ out) {
    int b   = blockIdx.x;
    int tid = threadIdx.x;
    __shared__ float pred[D];
    __shared__ float h0[DF], h1[DF], h2[DF];
    if (tid < D) {
        float acc = 0.f;
        const float* pb = part + (size_t)b * NCHUNK * D;
#pragma unroll 8
        for (int c = 0; c < NCHUNK; ++c) acc += pb[(size_t)c * D + tid];
        pred[tid] = acc;
    }
    __syncthreads();
    if (tid < DF) {
        float acc = b0[tid];
#pragma unroll 4
        for (int i = 0; i < D; ++i) acc += pred[i] * w0[i * DF + tid];
        h0[tid] = fmaxf(acc, 0.f);
    }
    __syncthreads();
    if (tid < DF) {
        float acc = b1[tid];
#pragma unroll 4
        for (int i = 0; i < DF; ++i) acc += h0[i] * w1[i * DF + tid];
        h1[tid] = fmaxf(acc, 0.f);
    }
    __syncthreads();
    if (tid < DF) {
        float acc = b2[tid];
#pragma unroll 4
        for (int i = 0; i < DF; ++i) acc += h1[i] * w2[i * DF + tid];
        h2[tid] = fmaxf(acc, 0.f);
    }
    __syncthreads();
    if (tid == 0) {
        float acc = b3[0];
        for (int i = 0; i < DF; ++i) acc += h2[i] * w3[i];
        out[b] = 1.f / (1.f + expf(-acc));
    }
}

// ---------------------------------------------------------------------------
extern "C" void kernel_launch(void* const* d_in, const int* in_sizes, int n_in,
                              void* d_out, int out_size, void* d_ws, size_t ws_size,
                              hipStream_t stream) {
    const float* c_hs  = (const float*)d_in[0];
    const float* adj1  = (const float*)d_in[1];
    const float* c_a2  = (const float*)d_in[2];
    const int*   valid = (const int*)d_in[3];
    const int*   nat   = (const int*)d_in[4];
    const float* Wemb  = (const float*)d_in[5];
    const float* gatW  = (const float*)d_in[6];
    const float* gatWb = (const float*)d_in[7];
    const float* gatA  = (const float*)d_in[8];
    const float* gatgw = (const float*)d_in[9];
    const float* gatgb = (const float*)d_in[10];
    const float* w0 = (const float*)d_in[11];
    const float* b0 = (const float*)d_in[12];
    const float* w1 = (const float*)d_in[13];
    const float* b1 = (const float*)d_in[14];
    const float* w2 = (const float*)d_in[15];
    const float* b2 = (const float*)d_in[16];
    const float* w3 = (const float*)d_in[17];
    const float* b3 = (const float*)d_in[18];
    const float* mu  = (const float*)d_in[19];
    const float* dev = (const float*)d_in[20];
    float* out = (float*)d_out;

    float* ws    = (float*)d_ws;
    float* adj2f = ws;                  // BNN
    float* Ebuf  = adj2f + BNN;         // BNN
    float* ATT   = Ebuf + BNN;          // BNN
    float* x     = ATT + BNN;           // BND
    float* h     = x + BND;             // BND
    float* hA    = h + BND;             // BND  (k_e operand; dead after k_e -> ath partial B)
    float* hp    = hA + BND;            // BND  (ath partial A)
    float* g1    = hp + BND;            // BND
    // total: 3*BNN + 5*BND floats = 147.7 MB
    // After the GAT loop, Ebuf is dead -> reuse as pooling partials
    float* part  = Ebuf;

    k_embed<<<(BND + 255) / 256, 256, 0, stream>>>(c_hs, Wemb, x);
    k_adj2<<<(BNN + 255) / 256, 256, 0, stream>>>(c_a2, valid, nat, mu, dev, adj2f);

    for (int l = 0; l < L; ++l) {
        const float* Wl  = gatW + (size_t)l * D * D;
        const float* Wbl = gatWb + (size_t)l * D;
        const float* Al  = gatA + (size_t)l * D * D;
        const float* gwl = gatgw + (size_t)l * 2 * D;
        const float* gbl = gatgb + l;

        k_linear140<<<(BND + 255) / 256, 256, 0, stream>>>(x, Wl, Wbl, h);
        k_linear140<<<(BND + 255) / 256, 256, 0, stream>>>(h, Al, nullptr, hA);
        k_e<<<dim3(N / 64, N / 64, B), 256, 0, stream>>>(h, hA, Ebuf);

        // gate 1: adj = c_adjs1   (hA is dead after k_e -> partial buffer)
        k_softmax<<<dim3(N / 64, B), 1024, 0, stream>>>(Ebuf, adj1, ATT);
        k_ath<<<dim3(N / 64, 3, B * JSPLIT), 192, 0, stream>>>(ATT, h, hp, hA);
        k_gate<<<B * N, 64, 0, stream>>>(x, hp, hA, gwl, gbl, g1, nullptr, 0);

        // gate 2: adj = adj2f; x = gate2 - gate1 (in place)
        k_softmax<<<dim3(N / 64, B), 1024, 0, stream>>>(Ebuf, adj2f, ATT);
        k_ath<<<dim3(N / 64, 3, B * JSPLIT), 192, 0, stream>>>(ATT, h, hp, hA);
        k_gate<<<B * N, 64, 0, stream>>>(x, hp, hA, gwl, gbl, g1, x, 1);
    }

    // two-stage ragged pool, then MLP head
    k_pool<<<dim3(NCHUNK, B), 256, 0, stream>>>(x, nat, part);
    k_final<<<B, 256, 0, stream>>>(part, w0, b0, w1, b1, w2, b2, w3, b3, out);
}

// Round 5
// 1867.184 us; speedup vs baseline: 1.6734x; 1.1043x over previous
//
#include <hip/hip_runtime.h>

// Problem constants
constexpr int B   = 16;
constexpr int N   = 768;
constexpr int FIN = 56;
constexpr int D   = 140;
constexpr int L   = 4;
constexpr int DF  = 128;
constexpr int NN  = N * N;        // 589824
constexpr int BND = B * N * D;    // 1720320
constexpr int BNN = B * NN;       // 9437184

// pooling split
constexpr int PROWS  = 16;            // rows per pooling block
constexpr int NCHUNK = N / PROWS;     // 48 partials per batch

// k_e tiling: K split 72+68 (16B-aligned chunk bases), 64x64 tiles
constexpr int NTILE = N / 64;         // 12
constexpr int NTRI  = NTILE * (NTILE + 1) / 2;  // 78 upper-triangle tiles

// k_ath tiling
constexpr int DT = 48;                // d-tile (140 -> 3 tiles of 48)
constexpr int JSPLIT = 2;             // j-halves -> partials in hp / hA

// ---------------------------------------------------------------------------
// K1: x = c_hs @ W_emb   [B*N,56] @ [56,140]
__global__ __launch_bounds__(256) void k_embed(const float* __restrict__ chs,
                                               const float* __restrict__ Wemb,
                                               float* __restrict__ x) {
    int idx = blockIdx.x * 256 + threadIdx.x;
    if (idx >= BND) return;
    int d  = idx % D;
    int bn = idx / D;
    const float* row = chs + bn * FIN;
    float acc = 0.f;
#pragma unroll 8
    for (int f = 0; f < FIN; ++f) acc += row[f] * Wemb[f * D + d];
    x[idx] = acc;
}

// ---------------------------------------------------------------------------
// K2: adj2 = formulate(c_adjs2)  (elementwise, mask from valid/num_atoms)
__global__ __launch_bounds__(256) void k_adj2(const float* __restrict__ a2,
                                              const int* __restrict__ valid,
                                              const int* __restrict__ natoms,
                                              const float* __restrict__ mu,
                                              const float* __restrict__ dev,
                                              float* __restrict__ out) {
    int idx = blockIdx.x * 256 + threadIdx.x;
    if (idx >= BNN) return;
    int b   = idx / NN;
    int rem = idx - b * NN;
    int i   = rem / N;
    int j   = rem - i * N;
    float a = a2[idx];
    int vi = valid[b * N + i];
    int vj = valid[b * N + j];
    int n  = natoms[b];
    bool mask = (vi && !vj && (j < n)) || (vj && !vi && (i < n));
    float dmu = a - mu[0];
    float g = (a <= 10.f) ? expf(-dmu * dmu / dev[0]) : 0.f;
    out[idx] = mask ? g : a;
}

// ---------------------------------------------------------------------------
// K3: out[bn,d] = in[bn,:] @ W[:,d] (+ bias)   — [B*N,140]@[140,140]
__global__ __launch_bounds__(256) void k_linear140(const float* __restrict__ in,
                                                   const float* __restrict__ W,
                                                   const float* __restrict__ bias,
                                                   float* __restrict__ out) {
    int idx = blockIdx.x * 256 + threadIdx.x;
    if (idx >= BND) return;
    int d  = idx % D;
    int bn = idx / D;
    const float* row = in + bn * D;
    float acc = bias ? bias[d] : 0.f;
#pragma unroll 4
    for (int k = 0; k < D; ++k) acc += row[k] * W[k * D + d];
    out[idx] = acc;
}

// ---------------------------------------------------------------------------
// K4: E[b,j,k] = hA[b,j,:]·h[b,k,:] + hA[b,k,:]·h[b,j,:]  (symmetric).
// Upper-triangle tiles launched directly (78 per batch, no idle blocks).
// Staging: 4x4 register block-transpose — float4 global loads + float4 LDS
// writes (was: scalar loads + 8-way-conflicted scalar column writes).
// K chunks 72/68 keep every 16B global window aligned. LDS 39.2KB -> 4 blk/CU.
__global__ __launch_bounds__(256) void k_e(const float* __restrict__ h,
                                           const float* __restrict__ hA,
                                           float* __restrict__ E) {
    int t = blockIdx.x;            // 0..77 linear upper-triangle index
    int b = blockIdx.y;
    int tj = 0, rem = t, rowlen = NTILE;
    while (rem >= rowlen) { rem -= rowlen; ++tj; --rowlen; }
    int tk = tj + rem;

    __shared__ float sJ[72][68];   // transposed j-tile chunk [c][j]
    __shared__ float sK[72][68];   // transposed k-tile chunk [c][j]
    int tid = threadIdx.x;
    int jg  = tid & 15;            // 16 j-groups x 4 j
    int kg  = tid >> 4;            // 16 k-groups x 4 k
    int j0 = tj * 64, k0 = tk * 64;
    const float* hb = h  + (size_t)b * N * D;
    const float* ab = hA + (size_t)b * N * D;

    float acc[4][4] = {};

    for (int r = 0; r < 4; ++r) {
        int ph = r >> 1;                  // 0: hA(j)·h(k), 1: h(j)·hA(k)
        int c0 = (r & 1) ? 72 : 0;
        int kc = (r & 1) ? 68 : 72;
        int ncb = kc >> 2;                // 18 or 17 c-blocks
        const float* uS = ph ? hb : ab;   // j-side source
        const float* vS = ph ? ab : hb;   // k-side source
        if (r) __syncthreads();
        // stage via 4x4 block transpose
        for (int idx = tid; idx < ncb * 16; idx += 256) {
            int cb = idx % ncb;
            int jb = (idx / ncb) * 4;     // 0,4,...,60
            int gc = c0 + cb * 4;
            float4 ru[4], rv[4];
#pragma unroll
            for (int s = 0; s < 4; ++s) {
                ru[s] = *reinterpret_cast<const float4*>(&uS[(size_t)(j0 + jb + s) * D + gc]);
                rv[s] = *reinterpret_cast<const float4*>(&vS[(size_t)(k0 + jb + s) * D + gc]);
            }
            float tu[4][4], tv[4][4];
#pragma unroll
            for (int s = 0; s < 4; ++s) {
                tu[s][0] = ru[s].x; tu[s][1] = ru[s].y; tu[s][2] = ru[s].z; tu[s][3] = ru[s].w;
                tv[s][0] = rv[s].x; tv[s][1] = rv[s].y; tv[s][2] = rv[s].z; tv[s][3] = rv[s].w;
            }
#pragma unroll
            for (int s = 0; s < 4; ++s) {
                float4 wu = {tu[0][s], tu[1][s], tu[2][s], tu[3][s]};
                float4 wv = {tv[0][s], tv[1][s], tv[2][s], tv[3][s]};
                *reinterpret_cast<float4*>(&sJ[cb * 4 + s][jb]) = wu;
                *reinterpret_cast<float4*>(&sK[cb * 4 + s][jb]) = wv;
            }
        }
        __syncthreads();
#pragma unroll 4
        for (int kk = 0; kk < kc; ++kk) {
            float4 ajv = *reinterpret_cast<const float4*>(&sJ[kk][jg * 4]);
            float4 akv = *reinterpret_cast<const float4*>(&sK[kk][kg * 4]);
            float aj[4] = {ajv.x, ajv.y, ajv.z, ajv.w};
            float ak[4] = {akv.x, akv.y, akv.z, akv.w};
#pragma unroll
            for (int i = 0; i < 4; ++i)
#pragma unroll
                for (int q = 0; q < 4; ++q) acc[i][q] += aj[i] * ak[q];
        }
    }

    float* Eb = E + (size_t)b * NN;
    int jb = j0 + jg * 4, kb = k0 + kg * 4;
#pragma unroll
    for (int i = 0; i < 4; ++i) {
        float4 v = {acc[i][0], acc[i][1], acc[i][2], acc[i][3]};
        *reinterpret_cast<float4*>(&Eb[(size_t)(jb + i) * N + kb]) = v;
    }
    // mirror: j-values per thread are contiguous -> also float4
#pragma unroll
    for (int q = 0; q < 4; ++q) {
        float4 v = {acc[0][q], acc[1][q], acc[2][q], acc[3][q]};
        *reinterpret_cast<float4*>(&Eb[(size_t)(kb + q) * N + jb]) = v;
    }
}

// ---------------------------------------------------------------------------
// K5: column softmax over axis j of masked E, times adj.
__global__ __launch_bounds__(1024) void k_softmax(const float* __restrict__ E,
                                                  const float* __restrict__ adj,
                                                  float* __restrict__ ATT) {
    int b    = blockIdx.y;
    int lane = threadIdx.x & 63;
    int js   = threadIdx.x >> 6;   // 0..15
    int k    = blockIdx.x * 64 + lane;
    const float* Eb = E   + (size_t)b * NN;
    const float* Ab = adj + (size_t)b * NN;
    float*       Tb = ATT + (size_t)b * NN;

    float m = -3.0e38f, s = 0.f;
    for (int j = js; j < N; j += 16) {
        float av = Ab[(size_t)j * N + k];
        float ev = Eb[(size_t)j * N + k];
        float x  = (av > 0.f) ? ev : -9e15f;
        float nm = fmaxf(m, x);
        s = s * __expf(m - nm) + __expf(x - nm);
        m = nm;
    }
    __shared__ float sm[16][64], ss[16][64];
    sm[js][lane] = m;
    ss[js][lane] = s;
    __syncthreads();
    if (js == 0) {
        float M = sm[0][lane], S = ss[0][lane];
#pragma unroll
        for (int q = 1; q < 16; ++q) {
            float m2 = sm[q][lane], s2 = ss[q][lane];
            float nm = fmaxf(M, m2);
            S = S * __expf(M - nm) + s2 * __expf(m2 - nm);
            M = nm;
        }
        sm[0][lane] = M;
        ss[0][lane] = 1.f / S;
    }
    __syncthreads();
    float M = sm[0][lane], invS = ss[0][lane];
    for (int j = js; j < N; j += 16) {
        float av = Ab[(size_t)j * N + k];
        float ev = Eb[(size_t)j * N + k];
        float x  = (av > 0.f) ? ev : -9e15f;
        Tb[(size_t)j * N + k] = __expf(x - M) * invS * av;
    }
}

// ---------------------------------------------------------------------------
// K6: partial of ATT @ h over half the j-range (NO relu here).
// js = blockIdx.z&1 selects j-half; partial -> pA (js=0) or pB (js=1, reusing
// the dead hA buffer). k_gate does relu(pA+pB).
__global__ __launch_bounds__(192) void k_ath(const float* __restrict__ ATT,
                                             const float* __restrict__ h,
                                             float* __restrict__ pA,
                                             float* __restrict__ pB) {
    int ti = blockIdx.x, td = blockIdx.y;
    int bz = blockIdx.z;
    int b  = bz >> 1;
    int js = bz & 1;
    __shared__ float sA[64][68];   // [j][i] transposed ATT tile
    __shared__ float sH[64][52];   // [j][d] h tile
    int tid = threadIdx.x;
    int ig  = tid & 15;            // 16 groups x 4 i
    int dg  = tid >> 4;            // 12 groups x 4 d
    int i0  = ti * 64, d0 = td * DT;
    const float* Tb = ATT + (size_t)b * NN;
    const float* hb = h   + (size_t)b * N * D;

    // staging indices for sH: 48 d-lanes x 4 j-rows
    int sd = tid % DT;             // 0..47
    int sj = tid / DT;             // 0..3
    int dd = d0 + sd;
    bool dok = (dd < D);

    float acc[4][4] = {};

    int jt0 = js * (N / 64 / JSPLIT);
    int jt1 = jt0 + (N / 64 / JSPLIT);
    for (int jt = jt0; jt < jt1; ++jt) {
        int j0 = jt * 64;
        if (jt != jt0) __syncthreads();
        // stage sA: ATT[i0+i][j0+j] -> sA[j][i]  (coalesced global read in j)
        for (int idx = tid; idx < 64 * 64; idx += 192) {
            int i = idx >> 6, j = idx & 63;
            sA[j][i] = Tb[(size_t)(i0 + i) * N + (j0 + j)];
        }
        // stage sH: h[j0+j][d0+sd] -> sH[j][sd]  (coalesced in d)
        for (int j = sj; j < 64; j += 4) {
            sH[j][sd] = dok ? hb[(size_t)(j0 + j) * D + dd] : 0.f;
        }
        __syncthreads();
#pragma unroll 4
        for (int kk = 0; kk < 64; ++kk) {
            float4 av = *reinterpret_cast<const float4*>(&sA[kk][ig * 4]);
            float4 hv = *reinterpret_cast<const float4*>(&sH[kk][dg * 4]);
            float ai[4] = {av.x, av.y, av.z, av.w};
            float hd[4] = {hv.x, hv.y, hv.z, hv.w};
#pragma unroll
            for (int i = 0; i < 4; ++i)
#pragma unroll
                for (int q = 0; q < 4; ++q) acc[i][q] += ai[i] * hd[q];
        }
    }

    int dw = d0 + dg * 4;
    if (dw < D) {
        float* dst = (js ? pB : pA) + (size_t)b * N * D;
#pragma unroll
        for (int i = 0; i < 4; ++i) {
            int row = i0 + ig * 4 + i;
            float4 v = {acc[i][0], acc[i][1], acc[i][2], acc[i][3]};
            *reinterpret_cast<float4*>(&dst[(size_t)row * D + dw]) = v;
        }
    }
}

// ---------------------------------------------------------------------------
// K7: gate combine; hp = relu(pA + pB) computed on the fly.
// mode 0: g1 = coeff*x+(1-coeff)*hp
// mode 1: x  = (coeff*x+(1-coeff)*hp) - g1   (in place)
__global__ __launch_bounds__(64) void k_gate(const float* __restrict__ x,
                                             const float* __restrict__ pA,
                                             const float* __restrict__ pB,
                                             const float* __restrict__ gw,
                                             const float* __restrict__ gb,
                                             float* __restrict__ g1,
                                             float* __restrict__ xout,
                                             int mode) {
    int row  = blockIdx.x;           // 0..B*N-1
    int lane = threadIdx.x;
    const float* xr = x  + (size_t)row * D;
    const float* pa = pA + (size_t)row * D;
    const float* pb = pB + (size_t)row * D;
    float xv[3], hv[3];
    float part = 0.f;
#pragma unroll
    for (int q = 0; q < 3; ++q) {
        int d = lane + q * 64;
        xv[q] = 0.f; hv[q] = 0.f;
        if (d < D) {
            xv[q] = xr[d];
            hv[q] = fmaxf(pa[d] + pb[d], 0.f);
            part += xv[q] * gw[d] + hv[q] * gw[D + d];
        }
    }
#pragma unroll
    for (int off = 32; off; off >>= 1) part += __shfl_xor(part, off);
    float c = 1.f / (1.f + __expf(-(part + gb[0])));
#pragma unroll
    for (int q = 0; q < 3; ++q) {
        int d = lane + q * 64;
        if (d < D) {
            float v = c * xv[q] + (1.f - c) * hv[q];
            if (mode == 0) g1[(size_t)row * D + d] = v;
            else           xout[(size_t)row * D + d] = v - g1[(size_t)row * D + d];
        }
    }
}

// ---------------------------------------------------------------------------
// K8a: parallel ragged sum-pool, stage 1.
__global__ __launch_bounds__(256) void k_pool(const float* __restrict__ x,
                                              const int* __restrict__ natoms,
                                              float* __restrict__ part) {
    int c = blockIdx.x;              // chunk
    int b = blockIdx.y;              // batch
    int tid = threadIdx.x;
    if (tid >= D) return;
    int n  = natoms[b];
    int r0 = c * PROWS;
    int r1 = min(r0 + PROWS, n);
    const float* xb = x + (size_t)b * N * D;
    float acc = 0.f;
    for (int r = r0; r < r1; ++r) acc += xb[(size_t)r * D + tid];
    part[((size_t)b * NCHUNK + c) * D + tid] = acc;
}

// ---------------------------------------------------------------------------
// K8b: combine partials + 4-layer MLP + sigmoid. One block per batch.
__global__ __launch_bounds__(256) void k_final(const float* __restrict__ part,
                                               const float* __restrict__ w0, const float* __restrict__ b0,
                                               const float* __restrict__ w1, const float* __restrict__ b1,
                                               const float* __restrict__ w2, const float* __restrict__ b2,
                                               const float* __restrict__ w3, const float* __restrict__ b3,
                                               float* __restrict__ out) {
    int b   = blockIdx.x;
    int tid = threadIdx.x;
    __shared__ float pred[D];
    __shared__ float h0[DF], h1[DF], h2[DF];
    if (tid < D) {
        float acc = 0.f;
        const float* pb = part + (size_t)b * NCHUNK * D;
#pragma unroll 8
        for (int c = 0; c < NCHUNK; ++c) acc += pb[(size_t)c * D + tid];
        pred[tid] = acc;
    }
    __syncthreads();
    if (tid < DF) {
        float acc = b0[tid];
#pragma unroll 4
        for (int i = 0; i < D; ++i) acc += pred[i] * w0[i * DF + tid];
        h0[tid] = fmaxf(acc, 0.f);
    }
    __syncthreads();
    if (tid < DF) {
        float acc = b1[tid];
#pragma unroll 4
        for (int i = 0; i < DF; ++i) acc += h0[i] * w1[i * DF + tid];
        h1[tid] = fmaxf(acc, 0.f);
    }
    __syncthreads();
    if (tid < DF) {
        float acc = b2[tid];
#pragma unroll 4
        for (int i = 0; i < DF; ++i) acc += h1[i] * w2[i * DF + tid];
        h2[tid] = fmaxf(acc, 0.f);
    }
    __syncthreads();
    if (tid == 0) {
        float acc = b3[0];
        for (int i = 0; i < DF; ++i) acc += h2[i] * w3[i];
        out[b] = 1.f / (1.f + expf(-acc));
    }
}

// ---------------------------------------------------------------------------
extern "C" void kernel_launch(void* const* d_in, const int* in_sizes, int n_in,
                              void* d_out, int out_size, void* d_ws, size_t ws_size,
                              hipStream_t stream) {
    const float* c_hs  = (const float*)d_in[0];
    const float* adj1  = (const float*)d_in[1];
    const float* c_a2  = (const float*)d_in[2];
    const int*   valid = (const int*)d_in[3];
    const int*   nat   = (const int*)d_in[4];
    const float* Wemb  = (const float*)d_in[5];
    const float* gatW  = (const float*)d_in[6];
    const float* gatWb = (const float*)d_in[7];
    const float* gatA  = (const float*)d_in[8];
    const float* gatgw = (const float*)d_in[9];
    const float* gatgb = (const float*)d_in[10];
    const float* w0 = (const float*)d_in[11];
    const float* b0 = (const float*)d_in[12];
    const float* w1 = (const float*)d_in[13];
    const float* b1 = (const float*)d_in[14];
    const float* w2 = (const float*)d_in[15];
    const float* b2 = (const float*)d_in[16];
    const float* w3 = (const float*)d_in[17];
    const float* b3 = (const float*)d_in[18];
    const float* mu  = (const float*)d_in[19];
    const float* dev = (const float*)d_in[20];
    float* out = (float*)d_out;

    float* ws    = (float*)d_ws;
    float* adj2f = ws;                  // BNN
    float* Ebuf  = adj2f + BNN;         // BNN
    float* ATT   = Ebuf + BNN;          // BNN
    float* x     = ATT + BNN;           // BND
    float* h     = x + BND;             // BND
    float* hA    = h + BND;             // BND  (k_e operand; dead after k_e -> ath partial B)
    float* hp    = hA + BND;            // BND  (ath partial A)
    float* g1    = hp + BND;            // BND
    // total: 3*BNN + 5*BND floats = 147.7 MB
    // After the GAT loop, Ebuf is dead -> reuse as pooling partials
    float* part  = Ebuf;

    k_embed<<<(BND + 255) / 256, 256, 0, stream>>>(c_hs, Wemb, x);
    k_adj2<<<(BNN + 255) / 256, 256, 0, stream>>>(c_a2, valid, nat, mu, dev, adj2f);

    for (int l = 0; l < L; ++l) {
        const float* Wl  = gatW + (size_t)l * D * D;
        const float* Wbl = gatWb + (size_t)l * D;
        const float* Al  = gatA + (size_t)l * D * D;
        const float* gwl = gatgw + (size_t)l * 2 * D;
        const float* gbl = gatgb + l;

        k_linear140<<<(BND + 255) / 256, 256, 0, stream>>>(x, Wl, Wbl, h);
        k_linear140<<<(BND + 255) / 256, 256, 0, stream>>>(h, Al, nullptr, hA);
        k_e<<<dim3(NTRI, B), 256, 0, stream>>>(h, hA, Ebuf);

        // gate 1: adj = c_adjs1   (hA is dead after k_e -> partial buffer)
        k_softmax<<<dim3(N / 64, B), 1024, 0, stream>>>(Ebuf, adj1, ATT);
        k_ath<<<dim3(N / 64, 3, B * JSPLIT), 192, 0, stream>>>(ATT, h, hp, hA);
        k_gate<<<B * N, 64, 0, stream>>>(x, hp, hA, gwl, gbl, g1, nullptr, 0);

        // gate 2: adj = adj2f; x = gate2 - gate1 (in place)
        k_softmax<<<dim3(N / 64, B), 1024, 0, stream>>>(Ebuf, adj2f, ATT);
        k_ath<<<dim3(N / 64, 3, B * JSPLIT), 192, 0, stream>>>(ATT, h, hp, hA);
        k_gate<<<B * N, 64, 0, stream>>>(x, hp, hA, gwl, gbl, g1, x, 1);
    }

    // two-stage ragged pool, then MLP head
    k_pool<<<dim3(NCHUNK, B), 256, 0, stream>>>(x, nat, part);
    k_final<<<B, 256, 0, stream>>>(part, w0, b0, w1, b1, w2, b2, w3, b3, out);
}

// Round 6
// 1806.694 us; speedup vs baseline: 1.7294x; 1.0335x over previous
//
#include <hip/hip_runtime.h>

// Problem constants
constexpr int B   = 16;
constexpr int N   = 768;
constexpr int FIN = 56;
constexpr int D   = 140;
constexpr int L   = 4;
constexpr int DF  = 128;
constexpr int NN  = N * N;        // 589824
constexpr int BND = B * N * D;    // 1720320
constexpr int BNN = B * NN;       // 9437184

// pooling split
constexpr int PROWS  = 16;            // rows per pooling block
constexpr int NCHUNK = N / PROWS;     // 48 partials per batch

// k_e tiling: K split 72+68 (16B-aligned chunk bases), 64x64 tiles
constexpr int NTILE = N / 64;         // 12
constexpr int NTRI  = NTILE * (NTILE + 1) / 2;  // 78 upper-triangle tiles

// k_ath tiling: 128i x 48d block, 8i x 4d micro-tile, 4-way j-split
constexpr int DT = 48;                // d-tile (140 -> 3 tiles of 48)
constexpr int JSPLIT = 4;             // j-quarters -> partials hp/hA/pC/pD

// ---------------------------------------------------------------------------
// K1: x = c_hs @ W_emb   [B*N,56] @ [56,140]
__global__ __launch_bounds__(256) void k_embed(const float* __restrict__ chs,
                                               const float* __restrict__ Wemb,
                                               float* __restrict__ x) {
    int idx = blockIdx.x * 256 + threadIdx.x;
    if (idx >= BND) return;
    int d  = idx % D;
    int bn = idx / D;
    const float* row = chs + bn * FIN;
    float acc = 0.f;
#pragma unroll 8
    for (int f = 0; f < FIN; ++f) acc += row[f] * Wemb[f * D + d];
    x[idx] = acc;
}

// ---------------------------------------------------------------------------
// K2: adj2 = formulate(c_adjs2)  (elementwise, mask from valid/num_atoms)
__global__ __launch_bounds__(256) void k_adj2(const float* __restrict__ a2,
                                              const int* __restrict__ valid,
                                              const int* __restrict__ natoms,
                                              const float* __restrict__ mu,
                                              const float* __restrict__ dev,
                                              float* __restrict__ out) {
    int idx = blockIdx.x * 256 + threadIdx.x;
    if (idx >= BNN) return;
    int b   = idx / NN;
    int rem = idx - b * NN;
    int i   = rem / N;
    int j   = rem - i * N;
    float a = a2[idx];
    int vi = valid[b * N + i];
    int vj = valid[b * N + j];
    int n  = natoms[b];
    bool mask = (vi && !vj && (j < n)) || (vj && !vi && (i < n));
    float dmu = a - mu[0];
    float g = (a <= 10.f) ? expf(-dmu * dmu / dev[0]) : 0.f;
    out[idx] = mask ? g : a;
}

// ---------------------------------------------------------------------------
// K3: out[bn,d] = in[bn,:] @ W[:,d] (+ bias)   — [B*N,140]@[140,140]
__global__ __launch_bounds__(256) void k_linear140(const float* __restrict__ in,
                                                   const float* __restrict__ W,
                                                   const float* __restrict__ bias,
                                                   float* __restrict__ out) {
    int idx = blockIdx.x * 256 + threadIdx.x;
    if (idx >= BND) return;
    int d  = idx % D;
    int bn = idx / D;
    const float* row = in + bn * D;
    float acc = bias ? bias[d] : 0.f;
#pragma unroll 4
    for (int k = 0; k < D; ++k) acc += row[k] * W[k * D + d];
    out[idx] = acc;
}

// ---------------------------------------------------------------------------
// K4: E[b,j,k] = hA[b,j,:]·h[b,k,:] + hA[b,k,:]·h[b,j,:]  (symmetric).
// Upper-triangle tiles launched directly (78 per batch, no idle blocks).
// Staging: 4x4 register block-transpose (float4 both sides).
__global__ __launch_bounds__(256) void k_e(const float* __restrict__ h,
                                           const float* __restrict__ hA,
                                           float* __restrict__ E) {
    int t = blockIdx.x;            // 0..77 linear upper-triangle index
    int b = blockIdx.y;
    int tj = 0, rem = t, rowlen = NTILE;
    while (rem >= rowlen) { rem -= rowlen; ++tj; --rowlen; }
    int tk = tj + rem;

    __shared__ float sJ[72][68];   // transposed j-tile chunk [c][j]
    __shared__ float sK[72][68];   // transposed k-tile chunk [c][j]
    int tid = threadIdx.x;
    int jg  = tid & 15;            // 16 j-groups x 4 j
    int kg  = tid >> 4;            // 16 k-groups x 4 k
    int j0 = tj * 64, k0 = tk * 64;
    const float* hb = h  + (size_t)b * N * D;
    const float* ab = hA + (size_t)b * N * D;

    float acc[4][4] = {};

    for (int r = 0; r < 4; ++r) {
        int ph = r >> 1;                  // 0: hA(j)·h(k), 1: h(j)·hA(k)
        int c0 = (r & 1) ? 72 : 0;
        int kc = (r & 1) ? 68 : 72;
        int ncb = kc >> 2;                // 18 or 17 c-blocks
        const float* uS = ph ? hb : ab;   // j-side source
        const float* vS = ph ? ab : hb;   // k-side source
        if (r) __syncthreads();
        // stage via 4x4 block transpose
        for (int idx = tid; idx < ncb * 16; idx += 256) {
            int cb = idx % ncb;
            int jb = (idx / ncb) * 4;     // 0,4,...,60
            int gc = c0 + cb * 4;
            float4 ru[4], rv[4];
#pragma unroll
            for (int s = 0; s < 4; ++s) {
                ru[s] = *reinterpret_cast<const float4*>(&uS[(size_t)(j0 + jb + s) * D + gc]);
                rv[s] = *reinterpret_cast<const float4*>(&vS[(size_t)(k0 + jb + s) * D + gc]);
            }
            float tu[4][4], tv[4][4];
#pragma unroll
            for (int s = 0; s < 4; ++s) {
                tu[s][0] = ru[s].x; tu[s][1] = ru[s].y; tu[s][2] = ru[s].z; tu[s][3] = ru[s].w;
                tv[s][0] = rv[s].x; tv[s][1] = rv[s].y; tv[s][2] = rv[s].z; tv[s][3] = rv[s].w;
            }
#pragma unroll
            for (int s = 0; s < 4; ++s) {
                float4 wu = {tu[0][s], tu[1][s], tu[2][s], tu[3][s]};
                float4 wv = {tv[0][s], tv[1][s], tv[2][s], tv[3][s]};
                *reinterpret_cast<float4*>(&sJ[cb * 4 + s][jb]) = wu;
                *reinterpret_cast<float4*>(&sK[cb * 4 + s][jb]) = wv;
            }
        }
        __syncthreads();
#pragma unroll 4
        for (int kk = 0; kk < kc; ++kk) {
            float4 ajv = *reinterpret_cast<const float4*>(&sJ[kk][jg * 4]);
            float4 akv = *reinterpret_cast<const float4*>(&sK[kk][kg * 4]);
            float aj[4] = {ajv.x, ajv.y, ajv.z, ajv.w};
            float ak[4] = {akv.x, akv.y, akv.z, akv.w};
#pragma unroll
            for (int i = 0; i < 4; ++i)
#pragma unroll
                for (int q = 0; q < 4; ++q) acc[i][q] += aj[i] * ak[q];
        }
    }

    float* Eb = E + (size_t)b * NN;
    int jb = j0 + jg * 4, kb = k0 + kg * 4;
#pragma unroll
    for (int i = 0; i < 4; ++i) {
        float4 v = {acc[i][0], acc[i][1], acc[i][2], acc[i][3]};
        *reinterpret_cast<float4*>(&Eb[(size_t)(jb + i) * N + kb]) = v;
    }
    // mirror: j-values per thread are contiguous -> also float4
#pragma unroll
    for (int q = 0; q < 4; ++q) {
        float4 v = {acc[0][q], acc[1][q], acc[2][q], acc[3][q]};
        *reinterpret_cast<float4*>(&Eb[(size_t)(kb + q) * N + jb]) = v;
    }
}

// ---------------------------------------------------------------------------
// K5: column softmax over axis j of masked E, times adj.
__global__ __launch_bounds__(1024) void k_softmax(const float* __restrict__ E,
                                                  const float* __restrict__ adj,
                                                  float* __restrict__ ATT) {
    int b    = blockIdx.y;
    int lane = threadIdx.x & 63;
    int js   = threadIdx.x >> 6;   // 0..15
    int k    = blockIdx.x * 64 + lane;
    const float* Eb = E   + (size_t)b * NN;
    const float* Ab = adj + (size_t)b * NN;
    float*       Tb = ATT + (size_t)b * NN;

    float m = -3.0e38f, s = 0.f;
    for (int j = js; j < N; j += 16) {
        float av = Ab[(size_t)j * N + k];
        float ev = Eb[(size_t)j * N + k];
        float x  = (av > 0.f) ? ev : -9e15f;
        float nm = fmaxf(m, x);
        s = s * __expf(m - nm) + __expf(x - nm);
        m = nm;
    }
    __shared__ float sm[16][64], ss[16][64];
    sm[js][lane] = m;
    ss[js][lane] = s;
    __syncthreads();
    if (js == 0) {
        float M = sm[0][lane], S = ss[0][lane];
#pragma unroll
        for (int q = 1; q < 16; ++q) {
            float m2 = sm[q][lane], s2 = ss[q][lane];
            float nm = fmaxf(M, m2);
            S = S * __expf(M - nm) + s2 * __expf(m2 - nm);
            M = nm;
        }
        sm[0][lane] = M;
        ss[0][lane] = 1.f / S;
    }
    __syncthreads();
    float M = sm[0][lane], invS = ss[0][lane];
    for (int j = js; j < N; j += 16) {
        float av = Ab[(size_t)j * N + k];
        float ev = Eb[(size_t)j * N + k];
        float x  = (av > 0.f) ? ev : -9e15f;
        Tb[(size_t)j * N + k] = __expf(x - M) * invS * av;
    }
}

// ---------------------------------------------------------------------------
// K6: partial of ATT @ h over a quarter of the j-range (NO relu here).
// 128i x 48d block, 192 threads, 8i x 4d micro-tile (i-frag split as rows
// ig*4+s and 64+ig*4+s so both LDS fragment reads are 2-way/free float4s).
// LDS bytes/flop: 0.75 (was 2.0) -> off the 69 TB/s LDS-BW roofline.
// sA staged via 4x4 register block-transpose (k_e pattern); sH via float4.
// js = blockIdx.z&3 selects j-quarter; partial -> p0..p3. k_gate sums+relu.
__global__ __launch_bounds__(192) void k_ath(const float* __restrict__ ATT,
                                             const float* __restrict__ h,
                                             float* __restrict__ p0,
                                             float* __restrict__ p1,
                                             float* __restrict__ p2,
                                             float* __restrict__ p3) {
    int ti = blockIdx.x;           // 0..5   (128-row i-tile)
    int td = blockIdx.y;           // 0..2   (48-col d-tile)
    int bz = blockIdx.z;
    int b  = bz >> 2;
    int js = bz & 3;
    __shared__ float sA[64][132];  // [j][i], i = 128 (+4 pad)
    __shared__ float sH[64][52];   // [j][d]
    int tid = threadIdx.x;
    int ig  = tid & 15;            // 16 i-groups
    int dg  = tid >> 4;            // 12 d-groups
    int i0  = ti * 128, d0 = td * DT;
    const float* Tb = ATT + (size_t)b * NN;
    const float* hb = h   + (size_t)b * N * D;

    float acc[8][4] = {};          // s<4: rows ig*4+s ; s>=4: rows 64+ig*4+(s-4)

    int jt0 = js * (N / 64 / JSPLIT);      // 3 j-tiles per block
    int jt1 = jt0 + (N / 64 / JSPLIT);
    for (int jt = jt0; jt < jt1; ++jt) {
        int j0 = jt * 64;
        if (jt != jt0) __syncthreads();
        // stage sA: 4x4 block transpose, ATT[i][j] -> sA[j][i]
        for (int idx = tid; idx < 512; idx += 192) {
            int jb4 = idx & 15;            // 16 j-blocks
            int ib4 = idx >> 4;            // 32 i-blocks
            float4 ru[4];
#pragma unroll
            for (int s = 0; s < 4; ++s)
                ru[s] = *reinterpret_cast<const float4*>(
                    &Tb[(size_t)(i0 + ib4 * 4 + s) * N + (j0 + jb4 * 4)]);
            float tu[4][4];
#pragma unroll
            for (int s = 0; s < 4; ++s) {
                tu[s][0] = ru[s].x; tu[s][1] = ru[s].y; tu[s][2] = ru[s].z; tu[s][3] = ru[s].w;
            }
#pragma unroll
            for (int s = 0; s < 4; ++s) {
                float4 wu = {tu[0][s], tu[1][s], tu[2][s], tu[3][s]};
                *reinterpret_cast<float4*>(&sA[jb4 * 4 + s][ib4 * 4]) = wu;
            }
        }
        // stage sH: float4 copy (D%4==0 -> no partial-vector case)
        for (int idx = tid; idx < 64 * 12; idx += 192) {
            int c4  = idx % 12;
            int row = idx / 12;
            int dd  = d0 + c4 * 4;
            float4 v = {0.f, 0.f, 0.f, 0.f};
            if (dd + 3 < D)
                v = *reinterpret_cast<const float4*>(&hb[(size_t)(j0 + row) * D + dd]);
            *reinterpret_cast<float4*>(&sH[row][c4 * 4]) = v;
        }
        __syncthreads();
#pragma unroll 4
        for (int kk = 0; kk < 64; ++kk) {
            float4 a0 = *reinterpret_cast<const float4*>(&sA[kk][ig * 4]);
            float4 a1 = *reinterpret_cast<const float4*>(&sA[kk][64 + ig * 4]);
            float4 hv = *reinterpret_cast<const float4*>(&sH[kk][dg * 4]);
            float ai[8] = {a0.x, a0.y, a0.z, a0.w, a1.x, a1.y, a1.z, a1.w};
            float hd[4] = {hv.x, hv.y, hv.z, hv.w};
#pragma unroll
            for (int i = 0; i < 8; ++i)
#pragma unroll
                for (int q = 0; q < 4; ++q) acc[i][q] += ai[i] * hd[q];
        }
    }

    int dw = d0 + dg * 4;
    if (dw < D) {
        float* dst = (js == 0 ? p0 : js == 1 ? p1 : js == 2 ? p2 : p3)
                     + (size_t)b * N * D;
#pragma unroll
        for (int s = 0; s < 8; ++s) {
            int row = i0 + ((s < 4) ? (ig * 4 + s) : (64 + ig * 4 + (s - 4)));
            float4 v = {acc[s][0], acc[s][1], acc[s][2], acc[s][3]};
            *reinterpret_cast<float4*>(&dst[(size_t)row * D + dw]) = v;
        }
    }
}

// ---------------------------------------------------------------------------
// K7: gate combine; hp = relu(p0+p1+p2+p3) computed on the fly.
// mode 0: g1 = coeff*x+(1-coeff)*hp
// mode 1: x  = (coeff*x+(1-coeff)*hp) - g1   (in place)
__global__ __launch_bounds__(64) void k_gate(const float* __restrict__ x,
                                             const float* __restrict__ p0,
                                             const float* __restrict__ p1,
                                             const float* __restrict__ p2,
                                             const float* __restrict__ p3,
                                             const float* __restrict__ gw,
                                             const float* __restrict__ gb,
                                             float* __restrict__ g1,
                                             float* __restrict__ xout,
                                             int mode) {
    int row  = blockIdx.x;           // 0..B*N-1
    int lane = threadIdx.x;
    const float* xr = x  + (size_t)row * D;
    const float* a0 = p0 + (size_t)row * D;
    const float* a1 = p1 + (size_t)row * D;
    const float* a2 = p2 + (size_t)row * D;
    const float* a3 = p3 + (size_t)row * D;
    float xv[3], hv[3];
    float part = 0.f;
#pragma unroll
    for (int q = 0; q < 3; ++q) {
        int d = lane + q * 64;
        xv[q] = 0.f; hv[q] = 0.f;
        if (d < D) {
            xv[q] = xr[d];
            hv[q] = fmaxf(a0[d] + a1[d] + a2[d] + a3[d], 0.f);
            part += xv[q] * gw[d] + hv[q] * gw[D + d];
        }
    }
#pragma unroll
    for (int off = 32; off; off >>= 1) part += __shfl_xor(part, off);
    float c = 1.f / (1.f + __expf(-(part + gb[0])));
#pragma unroll
    for (int q = 0; q < 3; ++q) {
        int d = lane + q * 64;
        if (d < D) {
            float v = c * xv[q] + (1.f - c) * hv[q];
            if (mode == 0) g1[(size_t)row * D + d] = v;
            else           xout[(size_t)row * D + d] = v - g1[(size_t)row * D + d];
        }
    }
}

// ---------------------------------------------------------------------------
// K8a: parallel ragged sum-pool, stage 1.
__global__ __launch_bounds__(256) void k_pool(const float* __restrict__ x,
                                              const int* __restrict__ natoms,
                                              float* __restrict__ part) {
    int c = blockIdx.x;              // chunk
    int b = blockIdx.y;              // batch
    int tid = threadIdx.x;
    if (tid >= D) return;
    int n  = natoms[b];
    int r0 = c * PROWS;
    int r1 = min(r0 + PROWS, n);
    const float* xb = x + (size_t)b * N * D;
    float acc = 0.f;
    for (int r = r0; r < r1; ++r) acc += xb[(size_t)r * D + tid];
    part[((size_t)b * NCHUNK + c) * D + tid] = acc;
}

// ---------------------------------------------------------------------------
// K8b: combine partials + 4-layer MLP + sigmoid. One block per batch.
__global__ __launch_bounds__(256) void k_final(const float* __restrict__ part,
                                               const float* __restrict__ w0, const float* __restrict__ b0,
                                               const float* __restrict__ w1, const float* __restrict__ b1,
                                               const float* __restrict__ w2, const float* __restrict__ b2,
                                               const float* __restrict__ w3, const float* __restrict__ b3,
                                               float* __restrict__ out) {
    int b   = blockIdx.x;
    int tid = threadIdx.x;
    __shared__ float pred[D];
    __shared__ float h0[DF], h1[DF], h2[DF];
    if (tid < D) {
        float acc = 0.f;
        const float* pb = part + (size_t)b * NCHUNK * D;
#pragma unroll 8
        for (int c = 0; c < NCHUNK; ++c) acc += pb[(size_t)c * D + tid];
        pred[tid] = acc;
    }
    __syncthreads();
    if (tid < DF) {
        float acc = b0[tid];
#pragma unroll 4
        for (int i = 0; i < D; ++i) acc += pred[i] * w0[i * DF + tid];
        h0[tid] = fmaxf(acc, 0.f);
    }
    __syncthreads();
    if (tid < DF) {
        float acc = b1[tid];
#pragma unroll 4
        for (int i = 0; i < DF; ++i) acc += h0[i] * w1[i * DF + tid];
        h1[tid] = fmaxf(acc, 0.f);
    }
    __syncthreads();
    if (tid < DF) {
        float acc = b2[tid];
#pragma unroll 4
        for (int i = 0; i < DF; ++i) acc += h1[i] * w2[i * DF + tid];
        h2[tid] = fmaxf(acc, 0.f);
    }
    __syncthreads();
    if (tid == 0) {
        float acc = b3[0];
        for (int i = 0; i < DF; ++i) acc += h2[i] * w3[i];
        out[b] = 1.f / (1.f + expf(-acc));
    }
}

// ---------------------------------------------------------------------------
extern "C" void kernel_launch(void* const* d_in, const int* in_sizes, int n_in,
                              void* d_out, int out_size, void* d_ws, size_t ws_size,
                              hipStream_t stream) {
    const float* c_hs  = (const float*)d_in[0];
    const float* adj1  = (const float*)d_in[1];
    const float* c_a2  = (const float*)d_in[2];
    const int*   valid = (const int*)d_in[3];
    const int*   nat   = (const int*)d_in[4];
    const float* Wemb  = (const float*)d_in[5];
    const float* gatW  = (const float*)d_in[6];
    const float* gatWb = (const float*)d_in[7];
    const float* gatA  = (const float*)d_in[8];
    const float* gatgw = (const float*)d_in[9];
    const float* gatgb = (const float*)d_in[10];
    const float* w0 = (const float*)d_in[11];
    const float* b0 = (const float*)d_in[12];
    const float* w1 = (const float*)d_in[13];
    const float* b1 = (const float*)d_in[14];
    const float* w2 = (const float*)d_in[15];
    const float* b2 = (const float*)d_in[16];
    const float* w3 = (const float*)d_in[17];
    const float* b3 = (const float*)d_in[18];
    const float* mu  = (const float*)d_in[19];
    const float* dev = (const float*)d_in[20];
    float* out = (float*)d_out;

    float* ws    = (float*)d_ws;
    float* adj2f = ws;                  // BNN
    float* Ebuf  = adj2f + BNN;         // BNN
    float* ATT   = Ebuf + BNN;          // BNN
    float* x     = ATT + BNN;           // BND
    float* h     = x + BND;             // BND
    float* hA    = h + BND;             // BND  (k_e operand; dead after k_e -> ath partial 1)
    float* hp    = hA + BND;            // BND  (ath partial 0)
    float* g1    = hp + BND;            // BND
    float* pC    = g1 + BND;            // BND  (ath partial 2)
    float* pD    = pC + BND;            // BND  (ath partial 3)
    // total: 3*BNN + 7*BND floats = 161.4 MB
    // After the GAT loop, Ebuf is dead -> reuse as pooling partials
    float* part  = Ebuf;

    k_embed<<<(BND + 255) / 256, 256, 0, stream>>>(c_hs, Wemb, x);
    k_adj2<<<(BNN + 255) / 256, 256, 0, stream>>>(c_a2, valid, nat, mu, dev, adj2f);

    for (int l = 0; l < L; ++l) {
        const float* Wl  = gatW + (size_t)l * D * D;
        const float* Wbl = gatWb + (size_t)l * D;
        const float* Al  = gatA + (size_t)l * D * D;
        const float* gwl = gatgw + (size_t)l * 2 * D;
        const float* gbl = gatgb + l;

        k_linear140<<<(BND + 255) / 256, 256, 0, stream>>>(x, Wl, Wbl, h);
        k_linear140<<<(BND + 255) / 256, 256, 0, stream>>>(h, Al, nullptr, hA);
        k_e<<<dim3(NTRI, B), 256, 0, stream>>>(h, hA, Ebuf);

        // gate 1: adj = c_adjs1   (hA is dead after k_e -> partial buffer)
        k_softmax<<<dim3(N / 64, B), 1024, 0, stream>>>(Ebuf, adj1, ATT);
        k_ath<<<dim3(N / 128, 3, B * JSPLIT), 192, 0, stream>>>(ATT, h, hp, hA, pC, pD);
        k_gate<<<B * N, 64, 0, stream>>>(x, hp, hA, pC, pD, gwl, gbl, g1, nullptr, 0);

        // gate 2: adj = adj2f; x = gate2 - gate1 (in place)
        k_softmax<<<dim3(N / 64, B), 1024, 0, stream>>>(Ebuf, adj2f, ATT);
        k_ath<<<dim3(N / 128, 3, B * JSPLIT), 192, 0, stream>>>(ATT, h, hp, hA, pC, pD);
        k_gate<<<B * N, 64, 0, stream>>>(x, hp, hA, pC, pD, gwl, gbl, g1, x, 1);
    }

    // two-stage ragged pool, then MLP head
    k_pool<<<dim3(NCHUNK, B), 256, 0, stream>>>(x, nat, part);
    k_final<<<B, 256, 0, stream>>>(part, w0, b0, w1, b1, w2, b2, w3, b3, out);
}

// Round 7
// 1593.309 us; speedup vs baseline: 1.9610x; 1.1339x over previous
//
#include <hip/hip_runtime.h>

// Problem constants
constexpr int B   = 16;
constexpr int N   = 768;
constexpr int FIN = 56;
constexpr int D   = 140;
constexpr int L   = 4;
constexpr int DF  = 128;
constexpr int NN  = N * N;        // 589824
constexpr int BND = B * N * D;    // 1720320
constexpr int BNN = B * NN;       // 9437184

// pooling split
constexpr int PROWS  = 16;            // rows per pooling block
constexpr int NCHUNK = N / PROWS;     // 48 partials per batch

// k_e tiling: K split 72+68 (16B-aligned chunk bases), 64x64 tiles
constexpr int NTILE = N / 64;         // 12
constexpr int NTRI  = NTILE * (NTILE + 1) / 2;  // 78 upper-triangle tiles

// k_ath tiling: 128i x 48d block, 8i x 4d micro-tile, 4-way j-split
constexpr int DT = 48;                // d-tile (140 -> 3 tiles of 48)
constexpr int JSPLIT = 4;             // j-quarters -> partials hp/hA/pC/pD

// ---------------------------------------------------------------------------
// K1/K3: out[r][d] = in[r][:K] @ W[:K][d] (+bias), out stride D.
// Register-blocked 4r x 4d micro-tile, no LDS. Per 4-k step: 4 float4 x-loads
// (near-broadcast in-wave: d varies fastest) + 4 float4 W-loads (coalesced,
// 560B span) + 64 FMAs -> 8:64 load:FMA (was 2:1 scalar -> issue-bound 13%).
template<int K>
__global__ __launch_bounds__(256) void k_linrb(const float* __restrict__ in,
                                               const float* __restrict__ W,
                                               const float* __restrict__ bias,
                                               float* __restrict__ out) {
    constexpr int NDG = D / 4;        // 35 d-groups
    int idx = blockIdx.x * 256 + threadIdx.x;
    if (idx >= (B * N / 4) * NDG) return;
    int dt = idx % NDG;               // d fastest -> x broadcast, W coalesced
    int rt = idx / NDG;
    int r0 = rt * 4, d = dt * 4;

    float acc[4][4];
    float b0 = 0.f, b1 = 0.f, b2 = 0.f, b3 = 0.f;
    if (bias) { b0 = bias[d]; b1 = bias[d + 1]; b2 = bias[d + 2]; b3 = bias[d + 3]; }
#pragma unroll
    for (int s = 0; s < 4; ++s) {
        acc[s][0] = b0; acc[s][1] = b1; acc[s][2] = b2; acc[s][3] = b3;
    }

#pragma unroll 2
    for (int k = 0; k < K; k += 4) {
        float4 wv[4];
#pragma unroll
        for (int kk = 0; kk < 4; ++kk)
            wv[kk] = *reinterpret_cast<const float4*>(&W[(size_t)(k + kk) * D + d]);
#pragma unroll
        for (int s = 0; s < 4; ++s) {
            float4 xv = *reinterpret_cast<const float4*>(&in[(size_t)(r0 + s) * K + k]);
            float xa[4] = {xv.x, xv.y, xv.z, xv.w};
#pragma unroll
            for (int kk = 0; kk < 4; ++kk) {
                acc[s][0] += xa[kk] * wv[kk].x;
                acc[s][1] += xa[kk] * wv[kk].y;
                acc[s][2] += xa[kk] * wv[kk].z;
                acc[s][3] += xa[kk] * wv[kk].w;
            }
        }
    }

#pragma unroll
    for (int s = 0; s < 4; ++s) {
        float4 v = {acc[s][0], acc[s][1], acc[s][2], acc[s][3]};
        *reinterpret_cast<float4*>(&out[(size_t)(r0 + s) * D + d]) = v;
    }
}

// ---------------------------------------------------------------------------
// K2: adj2 = formulate(c_adjs2)  (elementwise, mask from valid/num_atoms)
__global__ __launch_bounds__(256) void k_adj2(const float* __restrict__ a2,
                                              const int* __restrict__ valid,
                                              const int* __restrict__ natoms,
                                              const float* __restrict__ mu,
                                              const float* __restrict__ dev,
                                              float* __restrict__ out) {
    int idx = blockIdx.x * 256 + threadIdx.x;
    if (idx >= BNN) return;
    int b   = idx / NN;
    int rem = idx - b * NN;
    int i   = rem / N;
    int j   = rem - i * N;
    float a = a2[idx];
    int vi = valid[b * N + i];
    int vj = valid[b * N + j];
    int n  = natoms[b];
    bool mask = (vi && !vj && (j < n)) || (vj && !vi && (i < n));
    float dmu = a - mu[0];
    float g = (a <= 10.f) ? expf(-dmu * dmu / dev[0]) : 0.f;
    out[idx] = mask ? g : a;
}

// ---------------------------------------------------------------------------
// K4: E[b,j,k] = hA[b,j,:]·h[b,k,:] + hA[b,k,:]·h[b,j,:]  (symmetric).
// Upper-triangle tiles launched directly (78 per batch, no idle blocks).
// Staging: 4x4 register block-transpose (float4 both sides).
__global__ __launch_bounds__(256) void k_e(const float* __restrict__ h,
                                           const float* __restrict__ hA,
                                           float* __restrict__ E) {
    int t = blockIdx.x;            // 0..77 linear upper-triangle index
    int b = blockIdx.y;
    int tj = 0, rem = t, rowlen = NTILE;
    while (rem >= rowlen) { rem -= rowlen; ++tj; --rowlen; }
    int tk = tj + rem;

    __shared__ float sJ[72][68];   // transposed j-tile chunk [c][j]
    __shared__ float sK[72][68];   // transposed k-tile chunk [c][j]
    int tid = threadIdx.x;
    int jg  = tid & 15;            // 16 j-groups x 4 j
    int kg  = tid >> 4;            // 16 k-groups x 4 k
    int j0 = tj * 64, k0 = tk * 64;
    const float* hb = h  + (size_t)b * N * D;
    const float* ab = hA + (size_t)b * N * D;

    float acc[4][4] = {};

    for (int r = 0; r < 4; ++r) {
        int ph = r >> 1;                  // 0: hA(j)·h(k), 1: h(j)·hA(k)
        int c0 = (r & 1) ? 72 : 0;
        int kc = (r & 1) ? 68 : 72;
        int ncb = kc >> 2;                // 18 or 17 c-blocks
        const float* uS = ph ? hb : ab;   // j-side source
        const float* vS = ph ? ab : hb;   // k-side source
        if (r) __syncthreads();
        // stage via 4x4 block transpose
        for (int idx = tid; idx < ncb * 16; idx += 256) {
            int cb = idx % ncb;
            int jb = (idx / ncb) * 4;     // 0,4,...,60
            int gc = c0 + cb * 4;
            float4 ru[4], rv[4];
#pragma unroll
            for (int s = 0; s < 4; ++s) {
                ru[s] = *reinterpret_cast<const float4*>(&uS[(size_t)(j0 + jb + s) * D + gc]);
                rv[s] = *reinterpret_cast<const float4*>(&vS[(size_t)(k0 + jb + s) * D + gc]);
            }
            float tu[4][4], tv[4][4];
#pragma unroll
            for (int s = 0; s < 4; ++s) {
                tu[s][0] = ru[s].x; tu[s][1] = ru[s].y; tu[s][2] = ru[s].z; tu[s][3] = ru[s].w;
                tv[s][0] = rv[s].x; tv[s][1] = rv[s].y; tv[s][2] = rv[s].z; tv[s][3] = rv[s].w;
            }
#pragma unroll
            for (int s = 0; s < 4; ++s) {
                float4 wu = {tu[0][s], tu[1][s], tu[2][s], tu[3][s]};
                float4 wv = {tv[0][s], tv[1][s], tv[2][s], tv[3][s]};
                *reinterpret_cast<float4*>(&sJ[cb * 4 + s][jb]) = wu;
                *reinterpret_cast<float4*>(&sK[cb * 4 + s][jb]) = wv;
            }
        }
        __syncthreads();
#pragma unroll 4
        for (int kk = 0; kk < kc; ++kk) {
            float4 ajv = *reinterpret_cast<const float4*>(&sJ[kk][jg * 4]);
            float4 akv = *reinterpret_cast<const float4*>(&sK[kk][kg * 4]);
            float aj[4] = {ajv.x, ajv.y, ajv.z, ajv.w};
            float ak[4] = {akv.x, akv.y, akv.z, akv.w};
#pragma unroll
            for (int i = 0; i < 4; ++i)
#pragma unroll
                for (int q = 0; q < 4; ++q) acc[i][q] += aj[i] * ak[q];
        }
    }

    float* Eb = E + (size_t)b * NN;
    int jb = j0 + jg * 4, kb = k0 + kg * 4;
#pragma unroll
    for (int i = 0; i < 4; ++i) {
        float4 v = {acc[i][0], acc[i][1], acc[i][2], acc[i][3]};
        *reinterpret_cast<float4*>(&Eb[(size_t)(jb + i) * N + kb]) = v;
    }
    // mirror: j-values per thread are contiguous -> also float4
#pragma unroll
    for (int q = 0; q < 4; ++q) {
        float4 v = {acc[0][q], acc[1][q], acc[2][q], acc[3][q]};
        *reinterpret_cast<float4*>(&Eb[(size_t)(kb + q) * N + jb]) = v;
    }
}

// ---------------------------------------------------------------------------
// K5: column softmax over axis j of masked E, times adj.
__global__ __launch_bounds__(1024) void k_softmax(const float* __restrict__ E,
                                                  const float* __restrict__ adj,
                                                  float* __restrict__ ATT) {
    int b    = blockIdx.y;
    int lane = threadIdx.x & 63;
    int js   = threadIdx.x >> 6;   // 0..15
    int k    = blockIdx.x * 64 + lane;
    const float* Eb = E   + (size_t)b * NN;
    const float* Ab = adj + (size_t)b * NN;
    float*       Tb = ATT + (size_t)b * NN;

    float m = -3.0e38f, s = 0.f;
    for (int j = js; j < N; j += 16) {
        float av = Ab[(size_t)j * N + k];
        float ev = Eb[(size_t)j * N + k];
        float x  = (av > 0.f) ? ev : -9e15f;
        float nm = fmaxf(m, x);
        s = s * __expf(m - nm) + __expf(x - nm);
        m = nm;
    }
    __shared__ float sm[16][64], ss[16][64];
    sm[js][lane] = m;
    ss[js][lane] = s;
    __syncthreads();
    if (js == 0) {
        float M = sm[0][lane], S = ss[0][lane];
#pragma unroll
        for (int q = 1; q < 16; ++q) {
            float m2 = sm[q][lane], s2 = ss[q][lane];
            float nm = fmaxf(M, m2);
            S = S * __expf(M - nm) + s2 * __expf(m2 - nm);
            M = nm;
        }
        sm[0][lane] = M;
        ss[0][lane] = 1.f / S;
    }
    __syncthreads();
    float M = sm[0][lane], invS = ss[0][lane];
    for (int j = js; j < N; j += 16) {
        float av = Ab[(size_t)j * N + k];
        float ev = Eb[(size_t)j * N + k];
        float x  = (av > 0.f) ? ev : -9e15f;
        Tb[(size_t)j * N + k] = __expf(x - M) * invS * av;
    }
}

// ---------------------------------------------------------------------------
// K6: partial of ATT @ h over a quarter of the j-range (NO relu here).
// 128i x 48d block, 192 threads, 8i x 4d micro-tile.
__global__ __launch_bounds__(192) void k_ath(const float* __restrict__ ATT,
                                             const float* __restrict__ h,
                                             float* __restrict__ p0,
                                             float* __restrict__ p1,
                                             float* __restrict__ p2,
                                             float* __restrict__ p3) {
    int ti = blockIdx.x;           // 0..5   (128-row i-tile)
    int td = blockIdx.y;           // 0..2   (48-col d-tile)
    int bz = blockIdx.z;
    int b  = bz >> 2;
    int js = bz & 3;
    __shared__ float sA[64][132];  // [j][i], i = 128 (+4 pad)
    __shared__ float sH[64][52];   // [j][d]
    int tid = threadIdx.x;
    int ig  = tid & 15;            // 16 i-groups
    int dg  = tid >> 4;            // 12 d-groups
    int i0  = ti * 128, d0 = td * DT;
    const float* Tb = ATT + (size_t)b * NN;
    const float* hb = h   + (size_t)b * N * D;

    float acc[8][4] = {};          // s<4: rows ig*4+s ; s>=4: rows 64+ig*4+(s-4)

    int jt0 = js * (N / 64 / JSPLIT);      // 3 j-tiles per block
    int jt1 = jt0 + (N / 64 / JSPLIT);
    for (int jt = jt0; jt < jt1; ++jt) {
        int j0 = jt * 64;
        if (jt != jt0) __syncthreads();
        // stage sA: 4x4 block transpose, ATT[i][j] -> sA[j][i]
        for (int idx = tid; idx < 512; idx += 192) {
            int jb4 = idx & 15;            // 16 j-blocks
            int ib4 = idx >> 4;            // 32 i-blocks
            float4 ru[4];
#pragma unroll
            for (int s = 0; s < 4; ++s)
                ru[s] = *reinterpret_cast<const float4*>(
                    &Tb[(size_t)(i0 + ib4 * 4 + s) * N + (j0 + jb4 * 4)]);
            float tu[4][4];
#pragma unroll
            for (int s = 0; s < 4; ++s) {
                tu[s][0] = ru[s].x; tu[s][1] = ru[s].y; tu[s][2] = ru[s].z; tu[s][3] = ru[s].w;
            }
#pragma unroll
            for (int s = 0; s < 4; ++s) {
                float4 wu = {tu[0][s], tu[1][s], tu[2][s], tu[3][s]};
                *reinterpret_cast<float4*>(&sA[jb4 * 4 + s][ib4 * 4]) = wu;
            }
        }
        // stage sH: float4 copy (D%4==0 -> no partial-vector case)
        for (int idx = tid; idx < 64 * 12; idx += 192) {
            int c4  = idx % 12;
            int row = idx / 12;
            int dd  = d0 + c4 * 4;
            float4 v = {0.f, 0.f, 0.f, 0.f};
            if (dd + 3 < D)
                v = *reinterpret_cast<const float4*>(&hb[(size_t)(j0 + row) * D + dd]);
            *reinterpret_cast<float4*>(&sH[row][c4 * 4]) = v;
        }
        __syncthreads();
#pragma unroll 4
        for (int kk = 0; kk < 64; ++kk) {
            float4 a0 = *reinterpret_cast<const float4*>(&sA[kk][ig * 4]);
            float4 a1 = *reinterpret_cast<const float4*>(&sA[kk][64 + ig * 4]);
            float4 hv = *reinterpret_cast<const float4*>(&sH[kk][dg * 4]);
            float ai[8] = {a0.x, a0.y, a0.z, a0.w, a1.x, a1.y, a1.z, a1.w};
            float hd[4] = {hv.x, hv.y, hv.z, hv.w};
#pragma unroll
            for (int i = 0; i < 8; ++i)
#pragma unroll
                for (int q = 0; q < 4; ++q) acc[i][q] += ai[i] * hd[q];
        }
    }

    int dw = d0 + dg * 4;
    if (dw < D) {
        float* dst = (js == 0 ? p0 : js == 1 ? p1 : js == 2 ? p2 : p3)
                     + (size_t)b * N * D;
#pragma unroll
        for (int s = 0; s < 8; ++s) {
            int row = i0 + ((s < 4) ? (ig * 4 + s) : (64 + ig * 4 + (s - 4)));
            float4 v = {acc[s][0], acc[s][1], acc[s][2], acc[s][3]};
            *reinterpret_cast<float4*>(&dst[(size_t)row * D + dw]) = v;
        }
    }
}

// ---------------------------------------------------------------------------
// K7: gate combine; hp = relu(p0+p1+p2+p3) computed on the fly.
// mode 0: g1 = coeff*x+(1-coeff)*hp
// mode 1: x  = (coeff*x+(1-coeff)*hp) - g1   (in place)
__global__ __launch_bounds__(64) void k_gate(const float* __restrict__ x,
                                             const float* __restrict__ p0,
                                             const float* __restrict__ p1,
                                             const float* __restrict__ p2,
                                             const float* __restrict__ p3,
                                             const float* __restrict__ gw,
                                             const float* __restrict__ gb,
                                             float* __restrict__ g1,
                                             float* __restrict__ xout,
                                             int mode) {
    int row  = blockIdx.x;           // 0..B*N-1
    int lane = threadIdx.x;
    const float* xr = x  + (size_t)row * D;
    const float* a0 = p0 + (size_t)row * D;
    const float* a1 = p1 + (size_t)row * D;
    const float* a2 = p2 + (size_t)row * D;
    const float* a3 = p3 + (size_t)row * D;
    float xv[3], hv[3];
    float part = 0.f;
#pragma unroll
    for (int q = 0; q < 3; ++q) {
        int d = lane + q * 64;
        xv[q] = 0.f; hv[q] = 0.f;
        if (d < D) {
            xv[q] = xr[d];
            hv[q] = fmaxf(a0[d] + a1[d] + a2[d] + a3[d], 0.f);
            part += xv[q] * gw[d] + hv[q] * gw[D + d];
        }
    }
#pragma unroll
    for (int off = 32; off; off >>= 1) part += __shfl_xor(part, off);
    float c = 1.f / (1.f + __expf(-(part + gb[0])));
#pragma unroll
    for (int q = 0; q < 3; ++q) {
        int d = lane + q * 64;
        if (d < D) {
            float v = c * xv[q] + (1.f - c) * hv[q];
            if (mode == 0) g1[(size_t)row * D + d] = v;
            else           xout[(size_t)row * D + d] = v - g1[(size_t)row * D + d];
        }
    }
}

// ---------------------------------------------------------------------------
// K8a: parallel ragged sum-pool, stage 1.
__global__ __launch_bounds__(256) void k_pool(const float* __restrict__ x,
                                              const int* __restrict__ natoms,
                                              float* __restrict__ part) {
    int c = blockIdx.x;              // chunk
    int b = blockIdx.y;              // batch
    int tid = threadIdx.x;
    if (tid >= D) return;
    int n  = natoms[b];
    int r0 = c * PROWS;
    int r1 = min(r0 + PROWS, n);
    const float* xb = x + (size_t)b * N * D;
    float acc = 0.f;
    for (int r = r0; r < r1; ++r) acc += xb[(size_t)r * D + tid];
    part[((size_t)b * NCHUNK + c) * D + tid] = acc;
}

// ---------------------------------------------------------------------------
// K8b: combine partials + 4-layer MLP + sigmoid. One block per batch.
__global__ __launch_bounds__(256) void k_final(const float* __restrict__ part,
                                               const float* __restrict__ w0, const float* __restrict__ b0,
                                               const float* __restrict__ w1, const float* __restrict__ b1,
                                               const float* __restrict__ w2, const float* __restrict__ b2,
                                               const float* __restrict__ w3, const float* __restrict__ b3,
                                               float* __restrict__ out) {
    int b   = blockIdx.x;
    int tid = threadIdx.x;
    __shared__ float pred[D];
    __shared__ float h0[DF], h1[DF], h2[DF];
    if (tid < D) {
        float acc = 0.f;
        const float* pb = part + (size_t)b * NCHUNK * D;
#pragma unroll 8
        for (int c = 0; c < NCHUNK; ++c) acc += pb[(size_t)c * D + tid];
        pred[tid] = acc;
    }
    __syncthreads();
    if (tid < DF) {
        float acc = b0[tid];
#pragma unroll 4
        for (int i = 0; i < D; ++i) acc += pred[i] * w0[i * DF + tid];
        h0[tid] = fmaxf(acc, 0.f);
    }
    __syncthreads();
    if (tid < DF) {
        float acc = b1[tid];
#pragma unroll 4
        for (int i = 0; i < DF; ++i) acc += h0[i] * w1[i * DF + tid];
        h1[tid] = fmaxf(acc, 0.f);
    }
    __syncthreads();
    if (tid < DF) {
        float acc = b2[tid];
#pragma unroll 4
        for (int i = 0; i < DF; ++i) acc += h1[i] * w2[i * DF + tid];
        h2[tid] = fmaxf(acc, 0.f);
    }
    __syncthreads();
    if (tid == 0) {
        float acc = b3[0];
        for (int i = 0; i < DF; ++i) acc += h2[i] * w3[i];
        out[b] = 1.f / (1.f + expf(-acc));
    }
}

// ---------------------------------------------------------------------------
extern "C" void kernel_launch(void* const* d_in, const int* in_sizes, int n_in,
                              void* d_out, int out_size, void* d_ws, size_t ws_size,
                              hipStream_t stream) {
    const float* c_hs  = (const float*)d_in[0];
    const float* adj1  = (const float*)d_in[1];
    const float* c_a2  = (const float*)d_in[2];
    const int*   valid = (const int*)d_in[3];
    const int*   nat   = (const int*)d_in[4];
    const float* Wemb  = (const float*)d_in[5];
    const float* gatW  = (const float*)d_in[6];
    const float* gatWb = (const float*)d_in[7];
    const float* gatA  = (const float*)d_in[8];
    const float* gatgw = (const float*)d_in[9];
    const float* gatgb = (const float*)d_in[10];
    const float* w0 = (const float*)d_in[11];
    const float* b0 = (const float*)d_in[12];
    const float* w1 = (const float*)d_in[13];
    const float* b1 = (const float*)d_in[14];
    const float* w2 = (const float*)d_in[15];
    const float* b2 = (const float*)d_in[16];
    const float* w3 = (const float*)d_in[17];
    const float* b3 = (const float*)d_in[18];
    const float* mu  = (const float*)d_in[19];
    const float* dev = (const float*)d_in[20];
    float* out = (float*)d_out;

    float* ws    = (float*)d_ws;
    float* adj2f = ws;                  // BNN
    float* Ebuf  = adj2f + BNN;         // BNN
    float* ATT   = Ebuf + BNN;          // BNN
    float* x     = ATT + BNN;           // BND
    float* h     = x + BND;             // BND
    float* hA    = h + BND;             // BND  (k_e operand; dead after k_e -> ath partial 1)
    float* hp    = hA + BND;            // BND  (ath partial 0)
    float* g1    = hp + BND;            // BND
    float* pC    = g1 + BND;            // BND  (ath partial 2)
    float* pD    = pC + BND;            // BND  (ath partial 3)
    // total: 3*BNN + 7*BND floats = 161.4 MB
    // After the GAT loop, Ebuf is dead -> reuse as pooling partials
    float* part  = Ebuf;

    constexpr int LIN_GRID = (B * N / 4) * (D / 4) / 256;   // 420 blocks exactly

    k_linrb<FIN><<<LIN_GRID, 256, 0, stream>>>(c_hs, Wemb, nullptr, x);
    k_adj2<<<(BNN + 255) / 256, 256, 0, stream>>>(c_a2, valid, nat, mu, dev, adj2f);

    for (int l = 0; l < L; ++l) {
        const float* Wl  = gatW + (size_t)l * D * D;
        const float* Wbl = gatWb + (size_t)l * D;
        const float* Al  = gatA + (size_t)l * D * D;
        const float* gwl = gatgw + (size_t)l * 2 * D;
        const float* gbl = gatgb + l;

        k_linrb<D><<<LIN_GRID, 256, 0, stream>>>(x, Wl, Wbl, h);
        k_linrb<D><<<LIN_GRID, 256, 0, stream>>>(h, Al, nullptr, hA);
        k_e<<<dim3(NTRI, B), 256, 0, stream>>>(h, hA, Ebuf);

        // gate 1: adj = c_adjs1   (hA is dead after k_e -> partial buffer)
        k_softmax<<<dim3(N / 64, B), 1024, 0, stream>>>(Ebuf, adj1, ATT);
        k_ath<<<dim3(N / 128, 3, B * JSPLIT), 192, 0, stream>>>(ATT, h, hp, hA, pC, pD);
        k_gate<<<B * N, 64, 0, stream>>>(x, hp, hA, pC, pD, gwl, gbl, g1, nullptr, 0);

        // gate 2: adj = adj2f; x = gate2 - gate1 (in place)
        k_softmax<<<dim3(N / 64, B), 1024, 0, stream>>>(Ebuf, adj2f, ATT);
        k_ath<<<dim3(N / 128, 3, B * JSPLIT), 192, 0, stream>>>(ATT, h, hp, hA, pC, pD);
        k_gate<<<B * N, 64, 0, stream>>>(x, hp, hA, pC, pD, gwl, gbl, g1, x, 1);
    }

    // two-stage ragged pool, then MLP head
    k_pool<<<dim3(NCHUNK, B), 256, 0, stream>>>(x, nat, part);
    k_final<<<B, 256, 0, stream>>>(part, w0, b0, w1, b1, w2, b2, w3, b3, out);
}

// Round 8
// 1535.772 us; speedup vs baseline: 2.0345x; 1.0375x over previous
//
#include <hip/hip_runtime.h>

// Problem constants
constexpr int B   = 16;
constexpr int N   = 768;
constexpr int FIN = 56;
constexpr int D   = 140;
constexpr int L   = 4;
constexpr int DF  = 128;
constexpr int NN  = N * N;        // 589824
constexpr int BND = B * N * D;    // 1720320
constexpr int BNN = B * NN;       // 9437184

// pooling split
constexpr int PROWS  = 16;            // rows per pooling block
constexpr int NCHUNK = N / PROWS;     // 48 partials per batch

// k_e tiling: K split 72+68 (16B-aligned chunk bases), 64x64 tiles
constexpr int NTILE = N / 64;         // 12
constexpr int NTRI  = NTILE * (NTILE + 1) / 2;  // 78 upper-triangle tiles

// k_athf tiling: 64i x 140d block, 4i x 12d micro-tile, 4-way j-split
constexpr int JSPLIT = 4;             // j-quarters -> partials hp/hA/pC/pD

// ---------------------------------------------------------------------------
// K1/K3: out[r][d] = in[r][:K] @ W[:K][d] (+bias), out stride D.
// Register-blocked 4r x 4d micro-tile, no LDS.
template<int K>
__global__ __launch_bounds__(256) void k_linrb(const float* __restrict__ in,
                                               const float* __restrict__ W,
                                               const float* __restrict__ bias,
                                               float* __restrict__ out) {
    constexpr int NDG = D / 4;        // 35 d-groups
    int idx = blockIdx.x * 256 + threadIdx.x;
    if (idx >= (B * N / 4) * NDG) return;
    int dt = idx % NDG;               // d fastest -> x broadcast, W coalesced
    int rt = idx / NDG;
    int r0 = rt * 4, d = dt * 4;

    float acc[4][4];
    float b0 = 0.f, b1 = 0.f, b2 = 0.f, b3 = 0.f;
    if (bias) { b0 = bias[d]; b1 = bias[d + 1]; b2 = bias[d + 2]; b3 = bias[d + 3]; }
#pragma unroll
    for (int s = 0; s < 4; ++s) {
        acc[s][0] = b0; acc[s][1] = b1; acc[s][2] = b2; acc[s][3] = b3;
    }

#pragma unroll 2
    for (int k = 0; k < K; k += 4) {
        float4 wv[4];
#pragma unroll
        for (int kk = 0; kk < 4; ++kk)
            wv[kk] = *reinterpret_cast<const float4*>(&W[(size_t)(k + kk) * D + d]);
#pragma unroll
        for (int s = 0; s < 4; ++s) {
            float4 xv = *reinterpret_cast<const float4*>(&in[(size_t)(r0 + s) * K + k]);
            float xa[4] = {xv.x, xv.y, xv.z, xv.w};
#pragma unroll
            for (int kk = 0; kk < 4; ++kk) {
                acc[s][0] += xa[kk] * wv[kk].x;
                acc[s][1] += xa[kk] * wv[kk].y;
                acc[s][2] += xa[kk] * wv[kk].z;
                acc[s][3] += xa[kk] * wv[kk].w;
            }
        }
    }

#pragma unroll
    for (int s = 0; s < 4; ++s) {
        float4 v = {acc[s][0], acc[s][1], acc[s][2], acc[s][3]};
        *reinterpret_cast<float4*>(&out[(size_t)(r0 + s) * D + d]) = v;
    }
}

// ---------------------------------------------------------------------------
// K2: adj2 = formulate(c_adjs2)  (elementwise, mask from valid/num_atoms)
__global__ __launch_bounds__(256) void k_adj2(const float* __restrict__ a2,
                                              const int* __restrict__ valid,
                                              const int* __restrict__ natoms,
                                              const float* __restrict__ mu,
                                              const float* __restrict__ dev,
                                              float* __restrict__ out) {
    int idx = blockIdx.x * 256 + threadIdx.x;
    if (idx >= BNN) return;
    int b   = idx / NN;
    int rem = idx - b * NN;
    int i   = rem / N;
    int j   = rem - i * N;
    float a = a2[idx];
    int vi = valid[b * N + i];
    int vj = valid[b * N + j];
    int n  = natoms[b];
    bool mask = (vi && !vj && (j < n)) || (vj && !vi && (i < n));
    float dmu = a - mu[0];
    float g = (a <= 10.f) ? expf(-dmu * dmu / dev[0]) : 0.f;
    out[idx] = mask ? g : a;
}

// ---------------------------------------------------------------------------
// K4: E[b,j,k] = hA[b,j,:]·h[b,k,:] + hA[b,k,:]·h[b,j,:]  (symmetric).
// Upper-triangle tiles launched directly (78 per batch, no idle blocks).
// Staging: 4x4 register block-transpose (float4 both sides).
__global__ __launch_bounds__(256) void k_e(const float* __restrict__ h,
                                           const float* __restrict__ hA,
                                           float* __restrict__ E) {
    int t = blockIdx.x;            // 0..77 linear upper-triangle index
    int b = blockIdx.y;
    int tj = 0, rem = t, rowlen = NTILE;
    while (rem >= rowlen) { rem -= rowlen; ++tj; --rowlen; }
    int tk = tj + rem;

    __shared__ float sJ[72][68];   // transposed j-tile chunk [c][j]
    __shared__ float sK[72][68];   // transposed k-tile chunk [c][j]
    int tid = threadIdx.x;
    int jg  = tid & 15;            // 16 j-groups x 4 j
    int kg  = tid >> 4;            // 16 k-groups x 4 k
    int j0 = tj * 64, k0 = tk * 64;
    const float* hb = h  + (size_t)b * N * D;
    const float* ab = hA + (size_t)b * N * D;

    float acc[4][4] = {};

    for (int r = 0; r < 4; ++r) {
        int ph = r >> 1;                  // 0: hA(j)·h(k), 1: h(j)·hA(k)
        int c0 = (r & 1) ? 72 : 0;
        int kc = (r & 1) ? 68 : 72;
        int ncb = kc >> 2;                // 18 or 17 c-blocks
        const float* uS = ph ? hb : ab;   // j-side source
        const float* vS = ph ? ab : hb;   // k-side source
        if (r) __syncthreads();
        // stage via 4x4 block transpose
        for (int idx = tid; idx < ncb * 16; idx += 256) {
            int cb = idx % ncb;
            int jb = (idx / ncb) * 4;     // 0,4,...,60
            int gc = c0 + cb * 4;
            float4 ru[4], rv[4];
#pragma unroll
            for (int s = 0; s < 4; ++s) {
                ru[s] = *reinterpret_cast<const float4*>(&uS[(size_t)(j0 + jb + s) * D + gc]);
                rv[s] = *reinterpret_cast<const float4*>(&vS[(size_t)(k0 + jb + s) * D + gc]);
            }
            float tu[4][4], tv[4][4];
#pragma unroll
            for (int s = 0; s < 4; ++s) {
                tu[s][0] = ru[s].x; tu[s][1] = ru[s].y; tu[s][2] = ru[s].z; tu[s][3] = ru[s].w;
                tv[s][0] = rv[s].x; tv[s][1] = rv[s].y; tv[s][2] = rv[s].z; tv[s][3] = rv[s].w;
            }
#pragma unroll
            for (int s = 0; s < 4; ++s) {
                float4 wu = {tu[0][s], tu[1][s], tu[2][s], tu[3][s]};
                float4 wv = {tv[0][s], tv[1][s], tv[2][s], tv[3][s]};
                *reinterpret_cast<float4*>(&sJ[cb * 4 + s][jb]) = wu;
                *reinterpret_cast<float4*>(&sK[cb * 4 + s][jb]) = wv;
            }
        }
        __syncthreads();
#pragma unroll 4
        for (int kk = 0; kk < kc; ++kk) {
            float4 ajv = *reinterpret_cast<const float4*>(&sJ[kk][jg * 4]);
            float4 akv = *reinterpret_cast<const float4*>(&sK[kk][kg * 4]);
            float aj[4] = {ajv.x, ajv.y, ajv.z, ajv.w};
            float ak[4] = {akv.x, akv.y, akv.z, akv.w};
#pragma unroll
            for (int i = 0; i < 4; ++i)
#pragma unroll
                for (int q = 0; q < 4; ++q) acc[i][q] += aj[i] * ak[q];
        }
    }

    float* Eb = E + (size_t)b * NN;
    int jb = j0 + jg * 4, kb = k0 + kg * 4;
#pragma unroll
    for (int i = 0; i < 4; ++i) {
        float4 v = {acc[i][0], acc[i][1], acc[i][2], acc[i][3]};
        *reinterpret_cast<float4*>(&Eb[(size_t)(jb + i) * N + kb]) = v;
    }
    // mirror: j-values per thread are contiguous -> also float4
#pragma unroll
    for (int q = 0; q < 4; ++q) {
        float4 v = {acc[0][q], acc[1][q], acc[2][q], acc[3][q]};
        *reinterpret_cast<float4*>(&Eb[(size_t)(kb + q) * N + jb]) = v;
    }
}

// ---------------------------------------------------------------------------
// K5: column softmax stats for BOTH adjacencies in one pass over E.
// For fixed (b,k): M = max_j masked(E[j][k]), S = sum_j exp(x - M).
// Online/combine order identical to the previous k_softmax -> bit-identical M,S.
__global__ __launch_bounds__(1024) void k_stats(const float* __restrict__ E,
                                                const float* __restrict__ a1,
                                                const float* __restrict__ a2,
                                                float* __restrict__ M1g, float* __restrict__ IS1g,
                                                float* __restrict__ M2g, float* __restrict__ IS2g) {
    int b    = blockIdx.y;
    int lane = threadIdx.x & 63;
    int js   = threadIdx.x >> 6;   // 0..15
    int k    = blockIdx.x * 64 + lane;
    const float* Eb = E  + (size_t)b * NN;
    const float* A1 = a1 + (size_t)b * NN;
    const float* A2 = a2 + (size_t)b * NN;

    float m1 = -3.0e38f, s1 = 0.f, m2 = -3.0e38f, s2 = 0.f;
    for (int j = js; j < N; j += 16) {
        float ev = Eb[(size_t)j * N + k];
        float v1 = A1[(size_t)j * N + k];
        float v2 = A2[(size_t)j * N + k];
        float x1 = (v1 > 0.f) ? ev : -9e15f;
        float x2 = (v2 > 0.f) ? ev : -9e15f;
        float n1 = fmaxf(m1, x1);
        s1 = s1 * __expf(m1 - n1) + __expf(x1 - n1);
        m1 = n1;
        float n2 = fmaxf(m2, x2);
        s2 = s2 * __expf(m2 - n2) + __expf(x2 - n2);
        m2 = n2;
    }
    __shared__ float sm1[16][64], ss1[16][64], sm2[16][64], ss2[16][64];
    sm1[js][lane] = m1; ss1[js][lane] = s1;
    sm2[js][lane] = m2; ss2[js][lane] = s2;
    __syncthreads();
    if (js == 0) {
        float M = sm1[0][lane], S = ss1[0][lane];
#pragma unroll
        for (int q = 1; q < 16; ++q) {
            float mq = sm1[q][lane], sq = ss1[q][lane];
            float nm = fmaxf(M, mq);
            S = S * __expf(M - nm) + sq * __expf(mq - nm);
            M = nm;
        }
        M1g[(size_t)b * N + k] = M;
        IS1g[(size_t)b * N + k] = 1.f / S;
        M = sm2[0][lane]; S = ss2[0][lane];
#pragma unroll
        for (int q = 1; q < 16; ++q) {
            float mq = sm2[q][lane], sq = ss2[q][lane];
            float nm = fmaxf(M, mq);
            S = S * __expf(M - nm) + sq * __expf(mq - nm);
            M = nm;
        }
        M2g[(size_t)b * N + k] = M;
        IS2g[(size_t)b * N + k] = 1.f / S;
    }
}

// ---------------------------------------------------------------------------
// K6: FUSED softmax + partial ATT@h over a quarter of the j-range.
// att(i,j) = adj>0 ? exp(E[i][j]-M[j])*invS[j]*adj : 0, computed during the
// 4x4 block-transpose staging (E and adj each read exactly ONCE per gate —
// the old path wrote ATT then read it 3x, plus a full softmax pass).
// 64i x 140d per block, 192 threads, 4i x 12d micro-tile. d-fragment LDS
// reads are 16-lane broadcasts (free); att^T b128 writes at the 8-cycle floor.
__global__ __launch_bounds__(192) void k_athf(const float* __restrict__ E,
                                              const float* __restrict__ adj,
                                              const float* __restrict__ Mg,
                                              const float* __restrict__ ISg,
                                              const float* __restrict__ h,
                                              float* __restrict__ p0,
                                              float* __restrict__ p1,
                                              float* __restrict__ p2,
                                              float* __restrict__ p3) {
    int ti = blockIdx.x;           // 0..11 (64-row i-tile)
    int bz = blockIdx.y;
    int b  = bz >> 2;
    int js = bz & 3;
    __shared__ float sA[64][68];   // [j][i] att^T tile
    __shared__ float sH[64][144];  // [j][d] h tile (cols 140..143 zero pad)
    __shared__ float sM[192], sIS[192];
    int tid = threadIdx.x;
    int ig  = tid & 15;            // 16 i-groups x 4 i
    int dg  = tid >> 4;            // 12 d-groups x 12 d
    int i0  = ti * 64;
    const float* Eb = E   + (size_t)b * NN;
    const float* Ab = adj + (size_t)b * NN;
    const float* hb = h   + (size_t)b * N * D;
    int jbase = js * (N / JSPLIT);         // 192-j quarter

    sM[tid]  = Mg[(size_t)b * N + jbase + tid];
    sIS[tid] = ISg[(size_t)b * N + jbase + tid];
    __syncthreads();

    float acc[4][12] = {};

    for (int jt = 0; jt < 3; ++jt) {
        int j0 = jbase + jt * 64;
        int jl = jt * 64;
        if (jt) __syncthreads();
        // stage att^T: 4x4 block transpose with fused masked-softmax
        for (int idx = tid; idx < 256; idx += 192) {
            int jb4 = idx & 15, ib4 = idx >> 4;
            float4 ev[4], av[4];
#pragma unroll
            for (int s = 0; s < 4; ++s) {
                size_t off = (size_t)(i0 + ib4 * 4 + s) * N + (j0 + jb4 * 4);
                ev[s] = *reinterpret_cast<const float4*>(&Eb[off]);
                av[s] = *reinterpret_cast<const float4*>(&Ab[off]);
            }
            float mj[4], isj[4];
#pragma unroll
            for (int c = 0; c < 4; ++c) {
                mj[c]  = sM[jl + jb4 * 4 + c];
                isj[c] = sIS[jl + jb4 * 4 + c];
            }
            float at[4][4];
#pragma unroll
            for (int s = 0; s < 4; ++s) {
                float ea[4] = {ev[s].x, ev[s].y, ev[s].z, ev[s].w};
                float aa[4] = {av[s].x, av[s].y, av[s].z, av[s].w};
#pragma unroll
                for (int c = 0; c < 4; ++c)
                    at[s][c] = (aa[c] > 0.f)
                             ? __expf(ea[c] - mj[c]) * isj[c] * aa[c] : 0.f;
            }
#pragma unroll
            for (int c = 0; c < 4; ++c) {
                float4 w = {at[0][c], at[1][c], at[2][c], at[3][c]};
                *reinterpret_cast<float4*>(&sA[jb4 * 4 + c][ib4 * 4]) = w;
            }
        }
        // stage h tile: 64 rows x 144 cols (float4; last col zero)
        for (int idx = tid; idx < 64 * 36; idx += 192) {
            int c4  = idx % 36;
            int row = idx / 36;
            int dd  = c4 * 4;
            float4 v = {0.f, 0.f, 0.f, 0.f};
            if (dd < D)
                v = *reinterpret_cast<const float4*>(&hb[(size_t)(j0 + row) * D + dd]);
            *reinterpret_cast<float4*>(&sH[row][dd]) = v;
        }
        __syncthreads();
#pragma unroll 2
        for (int kk = 0; kk < 64; ++kk) {
            float4 a4 = *reinterpret_cast<const float4*>(&sA[kk][ig * 4]);
            float4 h0 = *reinterpret_cast<const float4*>(&sH[kk][dg * 12]);
            float4 h1 = *reinterpret_cast<const float4*>(&sH[kk][dg * 12 + 4]);
            float4 h2 = *reinterpret_cast<const float4*>(&sH[kk][dg * 12 + 8]);
            float ai[4]  = {a4.x, a4.y, a4.z, a4.w};
            float hd[12] = {h0.x, h0.y, h0.z, h0.w,
                            h1.x, h1.y, h1.z, h1.w,
                            h2.x, h2.y, h2.z, h2.w};
#pragma unroll
            for (int i = 0; i < 4; ++i)
#pragma unroll
                for (int q = 0; q < 12; ++q) acc[i][q] += ai[i] * hd[q];
        }
    }

    float* dst = (js == 0 ? p0 : js == 1 ? p1 : js == 2 ? p2 : p3)
                 + (size_t)b * N * D;
#pragma unroll
    for (int s = 0; s < 4; ++s) {
        int row = i0 + ig * 4 + s;
#pragma unroll
        for (int t = 0; t < 3; ++t) {
            int cc = dg * 12 + t * 4;
            if (cc < D) {   // D%4==0 -> no partial float4
                float4 v = {acc[s][t * 4], acc[s][t * 4 + 1],
                            acc[s][t * 4 + 2], acc[s][t * 4 + 3]};
                *reinterpret_cast<float4*>(&dst[(size_t)row * D + cc]) = v;
            }
        }
    }
}

// ---------------------------------------------------------------------------
// K7: gate combine; hp = relu(p0+p1+p2+p3) computed on the fly.
// mode 0: g1 = coeff*x+(1-coeff)*hp
// mode 1: x  = (coeff*x+(1-coeff)*hp) - g1   (in place)
__global__ __launch_bounds__(64) void k_gate(const float* __restrict__ x,
                                             const float* __restrict__ p0,
                                             const float* __restrict__ p1,
                                             const float* __restrict__ p2,
                                             const float* __restrict__ p3,
                                             const float* __restrict__ gw,
                                             const float* __restrict__ gb,
                                             float* __restrict__ g1,
                                             float* __restrict__ xout,
                                             int mode) {
    int row  = blockIdx.x;           // 0..B*N-1
    int lane = threadIdx.x;
    const float* xr = x  + (size_t)row * D;
    const float* a0 = p0 + (size_t)row * D;
    const float* a1 = p1 + (size_t)row * D;
    const float* a2 = p2 + (size_t)row * D;
    const float* a3 = p3 + (size_t)row * D;
    float xv[3], hv[3];
    float part = 0.f;
#pragma unroll
    for (int q = 0; q < 3; ++q) {
        int d = lane + q * 64;
        xv[q] = 0.f; hv[q] = 0.f;
        if (d < D) {
            xv[q] = xr[d];
            hv[q] = fmaxf(a0[d] + a1[d] + a2[d] + a3[d], 0.f);
            part += xv[q] * gw[d] + hv[q] * gw[D + d];
        }
    }
#pragma unroll
    for (int off = 32; off; off >>= 1) part += __shfl_xor(part, off);
    float c = 1.f / (1.f + __expf(-(part + gb[0])));
#pragma unroll
    for (int q = 0; q < 3; ++q) {
        int d = lane + q * 64;
        if (d < D) {
            float v = c * xv[q] + (1.f - c) * hv[q];
            if (mode == 0) g1[(size_t)row * D + d] = v;
            else           xout[(size_t)row * D + d] = v - g1[(size_t)row * D + d];
        }
    }
}

// ---------------------------------------------------------------------------
// K8a: parallel ragged sum-pool, stage 1.
__global__ __launch_bounds__(256) void k_pool(const float* __restrict__ x,
                                              const int* __restrict__ natoms,
                                              float* __restrict__ part) {
    int c = blockIdx.x;              // chunk
    int b = blockIdx.y;              // batch
    int tid = threadIdx.x;
    if (tid >= D) return;
    int n  = natoms[b];
    int r0 = c * PROWS;
    int r1 = min(r0 + PROWS, n);
    const float* xb = x + (size_t)b * N * D;
    float acc = 0.f;
    for (int r = r0; r < r1; ++r) acc += xb[(size_t)r * D + tid];
    part[((size_t)b * NCHUNK + c) * D + tid] = acc;
}

// ---------------------------------------------------------------------------
// K8b: combine partials + 4-layer MLP + sigmoid. One block per batch.
__global__ __launch_bounds__(256) void k_final(const float* __restrict__ part,
                                               const float* __restrict__ w0, const float* __restrict__ b0,
                                               const float* __restrict__ w1, const float* __restrict__ b1,
                                               const float* __restrict__ w2, const float* __restrict__ b2,
                                               const float* __restrict__ w3, const float* __restrict__ b3,
                                               float* __restrict__ out) {
    int b   = blockIdx.x;
    int tid = threadIdx.x;
    __shared__ float pred[D];
    __shared__ float h0[DF], h1[DF], h2[DF];
    if (tid < D) {
        float acc = 0.f;
        const float* pb = part + (size_t)b * NCHUNK * D;
#pragma unroll 8
        for (int c = 0; c < NCHUNK; ++c) acc += pb[(size_t)c * D + tid];
        pred[tid] = acc;
    }
    __syncthreads();
    if (tid < DF) {
        float acc = b0[tid];
#pragma unroll 4
        for (int i = 0; i < D; ++i) acc += pred[i] * w0[i * DF + tid];
        h0[tid] = fmaxf(acc, 0.f);
    }
    __syncthreads();
    if (tid < DF) {
        float acc = b1[tid];
#pragma unroll 4
        for (int i = 0; i < DF; ++i) acc += h0[i] * w1[i * DF + tid];
        h1[tid] = fmaxf(acc, 0.f);
    }
    __syncthreads();
    if (tid < DF) {
        float acc = b2[tid];
#pragma unroll 4
        for (int i = 0; i < DF; ++i) acc += h1[i] * w2[i * DF + tid];
        h2[tid] = fmaxf(acc, 0.f);
    }
    __syncthreads();
    if (tid == 0) {
        float acc = b3[0];
        for (int i = 0; i < DF; ++i) acc += h2[i] * w3[i];
        out[b] = 1.f / (1.f + expf(-acc));
    }
}

// ---------------------------------------------------------------------------
extern "C" void kernel_launch(void* const* d_in, const int* in_sizes, int n_in,
                              void* d_out, int out_size, void* d_ws, size_t ws_size,
                              hipStream_t stream) {
    const float* c_hs  = (const float*)d_in[0];
    const float* adj1  = (const float*)d_in[1];
    const float* c_a2  = (const float*)d_in[2];
    const int*   valid = (const int*)d_in[3];
    const int*   nat   = (const int*)d_in[4];
    const float* Wemb  = (const float*)d_in[5];
    const float* gatW  = (const float*)d_in[6];
    const float* gatWb = (const float*)d_in[7];
    const float* gatA  = (const float*)d_in[8];
    const float* gatgw = (const float*)d_in[9];
    const float* gatgb = (const float*)d_in[10];
    const float* w0 = (const float*)d_in[11];
    const float* b0 = (const float*)d_in[12];
    const float* w1 = (const float*)d_in[13];
    const float* b1 = (const float*)d_in[14];
    const float* w2 = (const float*)d_in[15];
    const float* b2 = (const float*)d_in[16];
    const float* w3 = (const float*)d_in[17];
    const float* b3 = (const float*)d_in[18];
    const float* mu  = (const float*)d_in[19];
    const float* dev = (const float*)d_in[20];
    float* out = (float*)d_out;

    float* ws    = (float*)d_ws;
    float* adj2f = ws;                  // BNN
    float* Ebuf  = adj2f + BNN;         // BNN
    float* ATTws = Ebuf + BNN;          // BNN (old ATT slot -> stats arrays)
    float* x     = ATTws + BNN;         // BND
    float* h     = x + BND;             // BND
    float* hA    = h + BND;             // BND  (k_e operand; dead after k_e -> athf partial 1)
    float* hp    = hA + BND;            // BND  (athf partial 0)
    float* g1    = hp + BND;            // BND
    float* pC    = g1 + BND;            // BND  (athf partial 2)
    float* pD    = pC + BND;            // BND  (athf partial 3)
    // total: 3*BNN + 7*BND floats = 161.4 MB (unchanged)
    // stats arrays live in the dead ATT slot:
    float* M1  = ATTws;
    float* IS1 = ATTws + (size_t)B * N;
    float* M2  = ATTws + (size_t)2 * B * N;
    float* IS2 = ATTws + (size_t)3 * B * N;
    // After the GAT loop, Ebuf is dead -> reuse as pooling partials
    float* part  = Ebuf;

    constexpr int LIN_GRID = (B * N / 4) * (D / 4) / 256;   // 420 blocks exactly

    k_linrb<FIN><<<LIN_GRID, 256, 0, stream>>>(c_hs, Wemb, nullptr, x);
    k_adj2<<<(BNN + 255) / 256, 256, 0, stream>>>(c_a2, valid, nat, mu, dev, adj2f);

    for (int l = 0; l < L; ++l) {
        const float* Wl  = gatW + (size_t)l * D * D;
        const float* Wbl = gatWb + (size_t)l * D;
        const float* Al  = gatA + (size_t)l * D * D;
        const float* gwl = gatgw + (size_t)l * 2 * D;
        const float* gbl = gatgb + l;

        k_linrb<D><<<LIN_GRID, 256, 0, stream>>>(x, Wl, Wbl, h);
        k_linrb<D><<<LIN_GRID, 256, 0, stream>>>(h, Al, nullptr, hA);
        k_e<<<dim3(NTRI, B), 256, 0, stream>>>(h, hA, Ebuf);

        // one pass over E computes column stats for BOTH adjacencies
        k_stats<<<dim3(N / 64, B), 1024, 0, stream>>>(Ebuf, adj1, adj2f,
                                                      M1, IS1, M2, IS2);

        // gate 1: adj = c_adjs1   (hA is dead after k_e -> partial buffer)
        k_athf<<<dim3(NTILE, B * JSPLIT), 192, 0, stream>>>(Ebuf, adj1, M1, IS1,
                                                            h, hp, hA, pC, pD);
        k_gate<<<B * N, 64, 0, stream>>>(x, hp, hA, pC, pD, gwl, gbl, g1, nullptr, 0);

        // gate 2: adj = adj2f; x = gate2 - gate1 (in place)
        k_athf<<<dim3(NTILE, B * JSPLIT), 192, 0, stream>>>(Ebuf, adj2f, M2, IS2,
                                                            h, hp, hA, pC, pD);
        k_gate<<<B * N, 64, 0, stream>>>(x, hp, hA, pC, pD, gwl, gbl, g1, x, 1);
    }

    // two-stage ragged pool, then MLP head
    k_pool<<<dim3(NCHUNK, B), 256, 0, stream>>>(x, nat, part);
    k_final<<<B, 256, 0, stream>>>(part, w0, b0, w1, b1, w2, b2, w3, b3, out);
}

// Round 9
// 1384.007 us; speedup vs baseline: 2.2576x; 1.1097x over previous
//
#include <hip/hip_runtime.h>

// Problem constants
constexpr int B   = 16;
constexpr int N   = 768;
constexpr int FIN = 56;
constexpr int D   = 140;
constexpr int L   = 4;
constexpr int DF  = 128;
constexpr int NN  = N * N;        // 589824
constexpr int BND = B * N * D;    // 1720320
constexpr int BNN = B * NN;       // 9437184

// pooling split
constexpr int PROWS  = 16;            // rows per pooling block
constexpr int NCHUNK = N / PROWS;     // 48 partials per batch

// k_e tiling: K split 72+68 (16B-aligned chunk bases), 64x64 tiles
constexpr int NTILE = N / 64;         // 12
constexpr int NTRI  = NTILE * (NTILE + 1) / 2;  // 78 upper-triangle tiles

// k_athf tiling: 64i x 140d block, 4i x 12d micro-tile, 4-way j-split
constexpr int JSPLIT = 4;             // j-quarters -> partials hp/hA/pC/pD

// ---------------------------------------------------------------------------
// K1/K3: out[r][d] = in[r][:K] @ W[:K][d] (+bias), out stride D.
// Register-blocked 4r x 4d micro-tile, no LDS.
template<int K>
__global__ __launch_bounds__(256) void k_linrb(const float* __restrict__ in,
                                               const float* __restrict__ W,
                                               const float* __restrict__ bias,
                                               float* __restrict__ out) {
    constexpr int NDG = D / 4;        // 35 d-groups
    int idx = blockIdx.x * 256 + threadIdx.x;
    if (idx >= (B * N / 4) * NDG) return;
    int dt = idx % NDG;               // d fastest -> x broadcast, W coalesced
    int rt = idx / NDG;
    int r0 = rt * 4, d = dt * 4;

    float acc[4][4];
    float b0 = 0.f, b1 = 0.f, b2 = 0.f, b3 = 0.f;
    if (bias) { b0 = bias[d]; b1 = bias[d + 1]; b2 = bias[d + 2]; b3 = bias[d + 3]; }
#pragma unroll
    for (int s = 0; s < 4; ++s) {
        acc[s][0] = b0; acc[s][1] = b1; acc[s][2] = b2; acc[s][3] = b3;
    }

#pragma unroll 2
    for (int k = 0; k < K; k += 4) {
        float4 wv[4];
#pragma unroll
        for (int kk = 0; kk < 4; ++kk)
            wv[kk] = *reinterpret_cast<const float4*>(&W[(size_t)(k + kk) * D + d]);
#pragma unroll
        for (int s = 0; s < 4; ++s) {
            float4 xv = *reinterpret_cast<const float4*>(&in[(size_t)(r0 + s) * K + k]);
            float xa[4] = {xv.x, xv.y, xv.z, xv.w};
#pragma unroll
            for (int kk = 0; kk < 4; ++kk) {
                acc[s][0] += xa[kk] * wv[kk].x;
                acc[s][1] += xa[kk] * wv[kk].y;
                acc[s][2] += xa[kk] * wv[kk].z;
                acc[s][3] += xa[kk] * wv[kk].w;
            }
        }
    }

#pragma unroll
    for (int s = 0; s < 4; ++s) {
        float4 v = {acc[s][0], acc[s][1], acc[s][2], acc[s][3]};
        *reinterpret_cast<float4*>(&out[(size_t)(r0 + s) * D + d]) = v;
    }
}

// ---------------------------------------------------------------------------
// K2: adj2 = formulate(c_adjs2)  (elementwise, mask from valid/num_atoms)
__global__ __launch_bounds__(256) void k_adj2(const float* __restrict__ a2,
                                              const int* __restrict__ valid,
                                              const int* __restrict__ natoms,
                                              const float* __restrict__ mu,
                                              const float* __restrict__ dev,
                                              float* __restrict__ out) {
    int idx = blockIdx.x * 256 + threadIdx.x;
    if (idx >= BNN) return;
    int b   = idx / NN;
    int rem = idx - b * NN;
    int i   = rem / N;
    int j   = rem - i * N;
    float a = a2[idx];
    int vi = valid[b * N + i];
    int vj = valid[b * N + j];
    int n  = natoms[b];
    bool mask = (vi && !vj && (j < n)) || (vj && !vi && (i < n));
    float dmu = a - mu[0];
    float g = (a <= 10.f) ? expf(-dmu * dmu / dev[0]) : 0.f;
    out[idx] = mask ? g : a;
}

// ---------------------------------------------------------------------------
// K4: E[b,j,k] = hA[b,j,:]·h[b,k,:] + hA[b,k,:]·h[b,j,:]  (symmetric).
// Upper-triangle tiles launched directly (78 per batch, no idle blocks).
// Staging: 4x4 register block-transpose (float4 both sides).
__global__ __launch_bounds__(256) void k_e(const float* __restrict__ h,
                                           const float* __restrict__ hA,
                                           float* __restrict__ E) {
    int t = blockIdx.x;            // 0..77 linear upper-triangle index
    int b = blockIdx.y;
    int tj = 0, rem = t, rowlen = NTILE;
    while (rem >= rowlen) { rem -= rowlen; ++tj; --rowlen; }
    int tk = tj + rem;

    __shared__ float sJ[72][68];   // transposed j-tile chunk [c][j]
    __shared__ float sK[72][68];   // transposed k-tile chunk [c][j]
    int tid = threadIdx.x;
    int jg  = tid & 15;            // 16 j-groups x 4 j
    int kg  = tid >> 4;            // 16 k-groups x 4 k
    int j0 = tj * 64, k0 = tk * 64;
    const float* hb = h  + (size_t)b * N * D;
    const float* ab = hA + (size_t)b * N * D;

    float acc[4][4] = {};

    for (int r = 0; r < 4; ++r) {
        int ph = r >> 1;                  // 0: hA(j)·h(k), 1: h(j)·hA(k)
        int c0 = (r & 1) ? 72 : 0;
        int kc = (r & 1) ? 68 : 72;
        int ncb = kc >> 2;                // 18 or 17 c-blocks
        const float* uS = ph ? hb : ab;   // j-side source
        const float* vS = ph ? ab : hb;   // k-side source
        if (r) __syncthreads();
        // stage via 4x4 block transpose
        for (int idx = tid; idx < ncb * 16; idx += 256) {
            int cb = idx % ncb;
            int jb = (idx / ncb) * 4;     // 0,4,...,60
            int gc = c0 + cb * 4;
            float4 ru[4], rv[4];
#pragma unroll
            for (int s = 0; s < 4; ++s) {
                ru[s] = *reinterpret_cast<const float4*>(&uS[(size_t)(j0 + jb + s) * D + gc]);
                rv[s] = *reinterpret_cast<const float4*>(&vS[(size_t)(k0 + jb + s) * D + gc]);
            }
            float tu[4][4], tv[4][4];
#pragma unroll
            for (int s = 0; s < 4; ++s) {
                tu[s][0] = ru[s].x; tu[s][1] = ru[s].y; tu[s][2] = ru[s].z; tu[s][3] = ru[s].w;
                tv[s][0] = rv[s].x; tv[s][1] = rv[s].y; tv[s][2] = rv[s].z; tv[s][3] = rv[s].w;
            }
#pragma unroll
            for (int s = 0; s < 4; ++s) {
                float4 wu = {tu[0][s], tu[1][s], tu[2][s], tu[3][s]};
                float4 wv = {tv[0][s], tv[1][s], tv[2][s], tv[3][s]};
                *reinterpret_cast<float4*>(&sJ[cb * 4 + s][jb]) = wu;
                *reinterpret_cast<float4*>(&sK[cb * 4 + s][jb]) = wv;
            }
        }
        __syncthreads();
#pragma unroll 4
        for (int kk = 0; kk < kc; ++kk) {
            float4 ajv = *reinterpret_cast<const float4*>(&sJ[kk][jg * 4]);
            float4 akv = *reinterpret_cast<const float4*>(&sK[kk][kg * 4]);
            float aj[4] = {ajv.x, ajv.y, ajv.z, ajv.w};
            float ak[4] = {akv.x, akv.y, akv.z, akv.w};
#pragma unroll
            for (int i = 0; i < 4; ++i)
#pragma unroll
                for (int q = 0; q < 4; ++q) acc[i][q] += aj[i] * ak[q];
        }
    }

    float* Eb = E + (size_t)b * NN;
    int jb = j0 + jg * 4, kb = k0 + kg * 4;
#pragma unroll
    for (int i = 0; i < 4; ++i) {
        float4 v = {acc[i][0], acc[i][1], acc[i][2], acc[i][3]};
        *reinterpret_cast<float4*>(&Eb[(size_t)(jb + i) * N + kb]) = v;
    }
    // mirror: j-values per thread are contiguous -> also float4
#pragma unroll
    for (int q = 0; q < 4; ++q) {
        float4 v = {acc[0][q], acc[1][q], acc[2][q], acc[3][q]};
        *reinterpret_cast<float4*>(&Eb[(size_t)(kb + q) * N + jb]) = v;
    }
}

// ---------------------------------------------------------------------------
// K5: column softmax stats for BOTH adjacencies in one pass over E.
// Online/combine order identical to the original k_softmax -> bit-identical M,S.
__global__ __launch_bounds__(1024) void k_stats(const float* __restrict__ E,
                                                const float* __restrict__ a1,
                                                const float* __restrict__ a2,
                                                float* __restrict__ M1g, float* __restrict__ IS1g,
                                                float* __restrict__ M2g, float* __restrict__ IS2g) {
    int b    = blockIdx.y;
    int lane = threadIdx.x & 63;
    int js   = threadIdx.x >> 6;   // 0..15
    int k    = blockIdx.x * 64 + lane;
    const float* Eb = E  + (size_t)b * NN;
    const float* A1 = a1 + (size_t)b * NN;
    const float* A2 = a2 + (size_t)b * NN;

    float m1 = -3.0e38f, s1 = 0.f, m2 = -3.0e38f, s2 = 0.f;
    for (int j = js; j < N; j += 16) {
        float ev = Eb[(size_t)j * N + k];
        float v1 = A1[(size_t)j * N + k];
        float v2 = A2[(size_t)j * N + k];
        float x1 = (v1 > 0.f) ? ev : -9e15f;
        float x2 = (v2 > 0.f) ? ev : -9e15f;
        float n1 = fmaxf(m1, x1);
        s1 = s1 * __expf(m1 - n1) + __expf(x1 - n1);
        m1 = n1;
        float n2 = fmaxf(m2, x2);
        s2 = s2 * __expf(m2 - n2) + __expf(x2 - n2);
        m2 = n2;
    }
    __shared__ float sm1[16][64], ss1[16][64], sm2[16][64], ss2[16][64];
    sm1[js][lane] = m1; ss1[js][lane] = s1;
    sm2[js][lane] = m2; ss2[js][lane] = s2;
    __syncthreads();
    if (js == 0) {
        float M = sm1[0][lane], S = ss1[0][lane];
#pragma unroll
        for (int q = 1; q < 16; ++q) {
            float mq = sm1[q][lane], sq = ss1[q][lane];
            float nm = fmaxf(M, mq);
            S = S * __expf(M - nm) + sq * __expf(mq - nm);
            M = nm;
        }
        M1g[(size_t)b * N + k] = M;
        IS1g[(size_t)b * N + k] = 1.f / S;
        M = sm2[0][lane]; S = ss2[0][lane];
#pragma unroll
        for (int q = 1; q < 16; ++q) {
            float mq = sm2[q][lane], sq = ss2[q][lane];
            float nm = fmaxf(M, mq);
            S = S * __expf(M - nm) + sq * __expf(mq - nm);
            M = nm;
        }
        M2g[(size_t)b * N + k] = M;
        IS2g[(size_t)b * N + k] = 1.f / S;
    }
}

// ---------------------------------------------------------------------------
// K6: FUSED softmax + partial ATT@h over a quarter of the j-range.
// v2 (this round): (a) sH removed — the d-fragment reads are 16-lane
// broadcasts, so the inner loop reads h directly from global (L2-resident,
// same-address lanes coalesce to one request). LDS 55.8 -> 18.9 KB.
// (b) sA columns XOR-swizzled by ((row>>2)&7)<<2: transpose-writes were
// an 8-way bank conflict (stride 68: dRow=4 => dAddr=16 words mod 32);
// swizzled writes span 8 bank groups (2-way = free). Reads apply the same
// XOR (constant per kk) and keep their free broadcast pattern.
__global__ __launch_bounds__(192) void k_athf(const float* __restrict__ E,
                                              const float* __restrict__ adj,
                                              const float* __restrict__ Mg,
                                              const float* __restrict__ ISg,
                                              const float* __restrict__ h,
                                              float* __restrict__ p0,
                                              float* __restrict__ p1,
                                              float* __restrict__ p2,
                                              float* __restrict__ p3) {
    int ti = blockIdx.x;           // 0..11 (64-row i-tile)
    int bz = blockIdx.y;
    int b  = bz >> 2;
    int js = bz & 3;
    __shared__ float sA[64][68];   // [j][i] att^T tile (cols XOR-swizzled)
    __shared__ float sM[192], sIS[192];
    int tid = threadIdx.x;
    int ig  = tid & 15;            // 16 i-groups x 4 i
    int dg  = tid >> 4;            // 12 d-groups x 12 d
    int i0  = ti * 64;
    const float* Eb = E   + (size_t)b * NN;
    const float* Ab = adj + (size_t)b * NN;
    const float* hb = h   + (size_t)b * N * D;
    int jbase = js * (N / JSPLIT);         // 192-j quarter

    sM[tid]  = Mg[(size_t)b * N + jbase + tid];
    sIS[tid] = ISg[(size_t)b * N + jbase + tid];
    __syncthreads();

    float acc[4][12] = {};

    for (int jt = 0; jt < 3; ++jt) {
        int j0 = jbase + jt * 64;
        int jl = jt * 64;
        if (jt) __syncthreads();
        // stage att^T: 4x4 block transpose with fused masked-softmax
        for (int idx = tid; idx < 256; idx += 192) {
            int jb4 = idx & 15, ib4 = idx >> 4;
            float4 ev[4], av[4];
#pragma unroll
            for (int s = 0; s < 4; ++s) {
                size_t off = (size_t)(i0 + ib4 * 4 + s) * N + (j0 + jb4 * 4);
                ev[s] = *reinterpret_cast<const float4*>(&Eb[off]);
                av[s] = *reinterpret_cast<const float4*>(&Ab[off]);
            }
            float mj[4], isj[4];
#pragma unroll
            for (int c = 0; c < 4; ++c) {
                mj[c]  = sM[jl + jb4 * 4 + c];
                isj[c] = sIS[jl + jb4 * 4 + c];
            }
            float at[4][4];
#pragma unroll
            for (int s = 0; s < 4; ++s) {
                float ea[4] = {ev[s].x, ev[s].y, ev[s].z, ev[s].w};
                float aa[4] = {av[s].x, av[s].y, av[s].z, av[s].w};
#pragma unroll
                for (int c = 0; c < 4; ++c)
                    at[s][c] = (aa[c] > 0.f)
                             ? __expf(ea[c] - mj[c]) * isj[c] * aa[c] : 0.f;
            }
#pragma unroll
            for (int c = 0; c < 4; ++c) {
                int row = jb4 * 4 + c;
                int col = (ib4 * 4) ^ (((row >> 2) & 7) << 2);   // swizzle
                float4 w = {at[0][c], at[1][c], at[2][c], at[3][c]};
                *reinterpret_cast<float4*>(&sA[row][col]) = w;
            }
        }
        __syncthreads();
#pragma unroll 2
        for (int kk = 0; kk < 64; ++kk) {
            int col = (ig * 4) ^ (((kk >> 2) & 7) << 2);         // swizzle
            float4 a4 = *reinterpret_cast<const float4*>(&sA[kk][col]);
            const float* hrow = hb + (size_t)(j0 + kk) * D + dg * 12;
            float4 h0 = *reinterpret_cast<const float4*>(&hrow[0]);
            float4 h1 = *reinterpret_cast<const float4*>(&hrow[4]);
            float4 h2 = *reinterpret_cast<const float4*>(&hrow[8]);
            float ai[4]  = {a4.x, a4.y, a4.z, a4.w};
            float hd[12] = {h0.x, h0.y, h0.z, h0.w,
                            h1.x, h1.y, h1.z, h1.w,
                            h2.x, h2.y, h2.z, h2.w};
#pragma unroll
            for (int i = 0; i < 4; ++i)
#pragma unroll
                for (int q = 0; q < 12; ++q) acc[i][q] += ai[i] * hd[q];
        }
    }

    float* dst = (js == 0 ? p0 : js == 1 ? p1 : js == 2 ? p2 : p3)
                 + (size_t)b * N * D;
#pragma unroll
    for (int s = 0; s < 4; ++s) {
        int row = i0 + ig * 4 + s;
#pragma unroll
        for (int t = 0; t < 3; ++t) {
            int cc = dg * 12 + t * 4;
            if (cc < D) {   // dg=11,t=2 (cols 140..143) discarded
                float4 v = {acc[s][t * 4], acc[s][t * 4 + 1],
                            acc[s][t * 4 + 2], acc[s][t * 4 + 3]};
                *reinterpret_cast<float4*>(&dst[(size_t)row * D + cc]) = v;
            }
        }
    }
}

// ---------------------------------------------------------------------------
// K7: gate combine; hp = relu(p0+p1+p2+p3) computed on the fly.
// mode 0: g1 = coeff*x+(1-coeff)*hp
// mode 1: x  = (coeff*x+(1-coeff)*hp) - g1   (in place)
__global__ __launch_bounds__(64) void k_gate(const float* __restrict__ x,
                                             const float* __restrict__ p0,
                                             const float* __restrict__ p1,
                                             const float* __restrict__ p2,
                                             const float* __restrict__ p3,
                                             const float* __restrict__ gw,
                                             const float* __restrict__ gb,
                                             float* __restrict__ g1,
                                             float* __restrict__ xout,
                                             int mode) {
    int row  = blockIdx.x;           // 0..B*N-1
    int lane = threadIdx.x;
    const float* xr = x  + (size_t)row * D;
    const float* a0 = p0 + (size_t)row * D;
    const float* a1 = p1 + (size_t)row * D;
    const float* a2 = p2 + (size_t)row * D;
    const float* a3 = p3 + (size_t)row * D;
    float xv[3], hv[3];
    float part = 0.f;
#pragma unroll
    for (int q = 0; q < 3; ++q) {
        int d = lane + q * 64;
        xv[q] = 0.f; hv[q] = 0.f;
        if (d < D) {
            xv[q] = xr[d];
            hv[q] = fmaxf(a0[d] + a1[d] + a2[d] + a3[d], 0.f);
            part += xv[q] * gw[d] + hv[q] * gw[D + d];
        }
    }
#pragma unroll
    for (int off = 32; off; off >>= 1) part += __shfl_xor(part, off);
    float c = 1.f / (1.f + __expf(-(part + gb[0])));
#pragma unroll
    for (int q = 0; q < 3; ++q) {
        int d = lane + q * 64;
        if (d < D) {
            float v = c * xv[q] + (1.f - c) * hv[q];
            if (mode == 0) g1[(size_t)row * D + d] = v;
            else           xout[(size_t)row * D + d] = v - g1[(size_t)row * D + d];
        }
    }
}

// ---------------------------------------------------------------------------
// K8a: parallel ragged sum-pool, stage 1.
__global__ __launch_bounds__(256) void k_pool(const float* __restrict__ x,
                                              const int* __restrict__ natoms,
                                              float* __restrict__ part) {
    int c = blockIdx.x;              // chunk
    int b = blockIdx.y;              // batch
    int tid = threadIdx.x;
    if (tid >= D) return;
    int n  = natoms[b];
    int r0 = c * PROWS;
    int r1 = min(r0 + PROWS, n);
    const float* xb = x + (size_t)b * N * D;
    float acc = 0.f;
    for (int r = r0; r < r1; ++r) acc += xb[(size_t)r * D + tid];
    part[((size_t)b * NCHUNK + c) * D + tid] = acc;
}

// ---------------------------------------------------------------------------
// K8b: combine partials + 4-layer MLP + sigmoid. One block per batch.
__global__ __launch_bounds__(256) void k_final(const float* __restrict__ part,
                                               const float* __restrict__ w0, const float* __restrict__ b0,
                                               const float* __restrict__ w1, const float* __restrict__ b1,
                                               const float* __restrict__ w2, const float* __restrict__ b2,
                                               const float* __restrict__ w3, const float* __restrict__ b3,
                                               float* __restrict__ out) {
    int b   = blockIdx.x;
    int tid = threadIdx.x;
    __shared__ float pred[D];
    __shared__ float h0[DF], h1[DF], h2[DF];
    if (tid < D) {
        float acc = 0.f;
        const float* pb = part + (size_t)b * NCHUNK * D;
#pragma unroll 8
        for (int c = 0; c < NCHUNK; ++c) acc += pb[(size_t)c * D + tid];
        pred[tid] = acc;
    }
    __syncthreads();
    if (tid < DF) {
        float acc = b0[tid];
#pragma unroll 4
        for (int i = 0; i < D; ++i) acc += pred[i] * w0[i * DF + tid];
        h0[tid] = fmaxf(acc, 0.f);
    }
    __syncthreads();
    if (tid < DF) {
        float acc = b1[tid];
#pragma unroll 4
        for (int i = 0; i < DF; ++i) acc += h0[i] * w1[i * DF + tid];
        h1[tid] = fmaxf(acc, 0.f);
    }
    __syncthreads();
    if (tid < DF) {
        float acc = b2[tid];
#pragma unroll 4
        for (int i = 0; i < DF; ++i) acc += h1[i] * w2[i * DF + tid];
        h2[tid] = fmaxf(acc, 0.f);
    }
    __syncthreads();
    if (tid == 0) {
        float acc = b3[0];
        for (int i = 0; i < DF; ++i) acc += h2[i] * w3[i];
        out[b] = 1.f / (1.f + expf(-acc));
    }
}

// ---------------------------------------------------------------------------
extern "C" void kernel_launch(void* const* d_in, const int* in_sizes, int n_in,
                              void* d_out, int out_size, void* d_ws, size_t ws_size,
                              hipStream_t stream) {
    const float* c_hs  = (const float*)d_in[0];
    const float* adj1  = (const float*)d_in[1];
    const float* c_a2  = (const float*)d_in[2];
    const int*   valid = (const int*)d_in[3];
    const int*   nat   = (const int*)d_in[4];
    const float* Wemb  = (const float*)d_in[5];
    const float* gatW  = (const float*)d_in[6];
    const float* gatWb = (const float*)d_in[7];
    const float* gatA  = (const float*)d_in[8];
    const float* gatgw = (const float*)d_in[9];
    const float* gatgb = (const float*)d_in[10];
    const float* w0 = (const float*)d_in[11];
    const float* b0 = (const float*)d_in[12];
    const float* w1 = (const float*)d_in[13];
    const float* b1 = (const float*)d_in[14];
    const float* w2 = (const float*)d_in[15];
    const float* b2 = (const float*)d_in[16];
    const float* w3 = (const float*)d_in[17];
    const float* b3 = (const float*)d_in[18];
    const float* mu  = (const float*)d_in[19];
    const float* dev = (const float*)d_in[20];
    float* out = (float*)d_out;

    float* ws    = (float*)d_ws;
    float* adj2f = ws;                  // BNN
    float* Ebuf  = adj2f + BNN;         // BNN
    float* ATTws = Ebuf + BNN;          // BNN (old ATT slot -> stats arrays)
    float* x     = ATTws + BNN;         // BND
    float* h     = x + BND;             // BND
    float* hA    = h + BND;             // BND  (k_e operand; dead after k_e -> athf partial 1)
    float* hp    = hA + BND;            // BND  (athf partial 0)
    float* g1    = hp + BND;            // BND
    float* pC    = g1 + BND;            // BND  (athf partial 2)
    float* pD    = pC + BND;            // BND  (athf partial 3)
    // total: 3*BNN + 7*BND floats = 161.4 MB (unchanged)
    // stats arrays live in the dead ATT slot:
    float* M1  = ATTws;
    float* IS1 = ATTws + (size_t)B * N;
    float* M2  = ATTws + (size_t)2 * B * N;
    float* IS2 = ATTws + (size_t)3 * B * N;
    // After the GAT loop, Ebuf is dead -> reuse as pooling partials
    float* part  = Ebuf;

    constexpr int LIN_GRID = (B * N / 4) * (D / 4) / 256;   // 420 blocks exactly

    k_linrb<FIN><<<LIN_GRID, 256, 0, stream>>>(c_hs, Wemb, nullptr, x);
    k_adj2<<<(BNN + 255) / 256, 256, 0, stream>>>(c_a2, valid, nat, mu, dev, adj2f);

    for (int l = 0; l < L; ++l) {
        const float* Wl  = gatW + (size_t)l * D * D;
        const float* Wbl = gatWb + (size_t)l * D;
        const float* Al  = gatA + (size_t)l * D * D;
        const float* gwl = gatgw + (size_t)l * 2 * D;
        const float* gbl = gatgb + l;

        k_linrb<D><<<LIN_GRID, 256, 0, stream>>>(x, Wl, Wbl, h);
        k_linrb<D><<<LIN_GRID, 256, 0, stream>>>(h, Al, nullptr, hA);
        k_e<<<dim3(NTRI, B), 256, 0, stream>>>(h, hA, Ebuf);

        // one pass over E computes column stats for BOTH adjacencies
        k_stats<<<dim3(N / 64, B), 1024, 0, stream>>>(Ebuf, adj1, adj2f,
                                                      M1, IS1, M2, IS2);

        // gate 1: adj = c_adjs1   (hA is dead after k_e -> partial buffer)
        k_athf<<<dim3(NTILE, B * JSPLIT), 192, 0, stream>>>(Ebuf, adj1, M1, IS1,
                                                            h, hp, hA, pC, pD);
        k_gate<<<B * N, 64, 0, stream>>>(x, hp, hA, pC, pD, gwl, gbl, g1, nullptr, 0);

        // gate 2: adj = adj2f; x = gate2 - gate1 (in place)
        k_athf<<<dim3(NTILE, B * JSPLIT), 192, 0, stream>>>(Ebuf, adj2f, M2, IS2,
                                                            h, hp, hA, pC, pD);
        k_gate<<<B * N, 64, 0, stream>>>(x, hp, hA, pC, pD, gwl, gbl, g1, x, 1);
    }

    // two-stage ragged pool, then MLP head
    k_pool<<<dim3(NCHUNK, B), 256, 0, stream>>>(x, nat, part);
    k_final<<<B, 256, 0, stream>>>(part, w0, b0, w1, b1, w2, b2, w3, b3, out);
}